// Round 3
// baseline (823.607 us; speedup 1.0000x reference)
//
#include <hip/hip_runtime.h>
#include <hip/hip_bf16.h>

// GraphConvLayer B=4,N=128,D=512,H=8. Input dtype (bf16|fp32) runtime-detected
// -> flag in ws; output dtype follows input dtype.
// f==1: E pre-converted to bf16 into d_out's outE region, chunk-layout:
//   chunk c (64 rows) occupies bytes [1048576 + c*131072, +131072):
//   [Ebf16 64x1024B | u 64x1024B]. k6 block owns one chunk.
// f==0: E read from d_in (bf16); u chunks at dout+524288+c*65536.
// XCD-locality chain: cvt_edge, k3, k6 grids swizzled so chunk c is written and
// read on XCD (c>>1)&7 (k3 block bm -> XCD bm&7).
// r3 changes:
//  - k3 paired: block owns (bm, cb) and computes BOTH attn col-block (WtA) and
//    u col-block (WtB) off ONE staged E tile: 32 MFMA/barrier (was 16), A
//    traffic halved, 2048 blocks. LDS 76KB: A 3x8K | B 3x16K | We2 4K.
//    vmcnt(6) counted pipeline (6 loads/stage, 3-deep).
//  - fused5 -> fused5_mfma: 5 h-GEMMs as MFMA 128x128 tiles (80 blocks), h in
//    bf16 (hb from small_gemm), weights pre-transposed bf16 (transpose3 x8).
//  - node_fused: 4 rows/block (128 blocks), Wo traffic /4, shfl LN reductions.

typedef __bf16  bf16x8 __attribute__((ext_vector_type(8)));
typedef float   f32x4  __attribute__((ext_vector_type(4)));
typedef __hip_bfloat16 bfloat;

#define AS1 __attribute__((address_space(1)))
#define AS3 __attribute__((address_space(3)))

__device__ __forceinline__ void g2l16(const void* g, void* l) {
  __builtin_amdgcn_global_load_lds((AS1 void*)g, (AS3 void*)l, 16, 0, 0);
}

__device__ __forceinline__ float ldf(const void* p, size_t i, int f) {
  return f ? ((const float*)p)[i] : __bfloat162float(((const bfloat*)p)[i]);
}
__device__ __forceinline__ void stf(void* p, size_t i, float v, int f) {
  if (f) ((float*)p)[i] = v;
  else   ((bfloat*)p)[i] = __float2bfloat16(v);
}

// tanh-form GELU (max abs err ~3e-4 vs exact erf form; well under threshold)
__device__ __forceinline__ float gelu_f(float x) {
  float y = 0.7978845608028654f * (x + 0.044715f * x * x * x);
  float e = __expf(2.0f * y);
  float t = 1.0f - 2.0f / (e + 1.0f);
  return 0.5f * x * (1.0f + t);
}

__global__ __launch_bounds__(256) void detect_dtype(const unsigned short* nu, int* flag) {
  __shared__ int bad;
  if (threadIdx.x == 0) bad = 0;
  __syncthreads();
  int local = 0;
  for (int i = threadIdx.x; i < 4096; i += 256) {
    int ex = (nu[i] >> 7) & 0xFF;
    if (ex >= 0xC0) local = 1;
  }
  if (local) atomicOr(&bad, 1);
  __syncthreads();
  if (threadIdx.x == 0) *flag = bad;
}

// f==1 only: E fp32 -> bf16 chunk layout in dout. Grid 16384, XCD-aligned.
__global__ __launch_bounds__(256) void cvt_edge(const float* E, const int* flag, void* dout) {
  if (*flag == 0) return;
  const int e = blockIdx.x & 7;
  const int x = blockIdx.x >> 3;          // 0..2047
  const int m = x >> 5;                   // 0..63
  const int h = (x >> 4) & 1;
  const int s = x & 15;                   // 16 blocks per chunk
  const int c = 2 * e + 16 * m + h;       // chunk 0..1023
  const int t = threadIdx.x;
  const int rloc = s * 4 + (t >> 6);      // row within chunk 0..63
  const int c8 = t & 63;
  const float* src = E + ((size_t)c * 64 + rloc) * 512 + (size_t)c8 * 8;
  f32x4 lo = *(const f32x4*)src;
  f32x4 hi = *(const f32x4*)(src + 4);
  bf16x8 v;
  v[0] = (__bf16)lo[0]; v[1] = (__bf16)lo[1]; v[2] = (__bf16)lo[2]; v[3] = (__bf16)lo[3];
  v[4] = (__bf16)hi[0]; v[5] = (__bf16)hi[1]; v[6] = (__bf16)hi[2]; v[7] = (__bf16)hi[3];
  char* eb = (char*)dout + 1048576;
  *(bf16x8*)(eb + (size_t)c * 131072 + (size_t)rloc * 1024 + (size_t)c8 * 16) = v;
}

// 8 transposed bf16 weight copies (n-major [n][k]).
__global__ __launch_bounds__(256) void transpose3(const void* We1, const void* Wu1,
                                                  const void* Wu2, const void* Wm,
                                                  const int* flag,
                                                  bfloat* WtA, bfloat* WtB, bfloat* WtC,
                                                  bfloat* WtD, bfloat* WtE, bfloat* WtF,
                                                  bfloat* WtG, bfloat* WtH) {
  const int f = *flag;
  int idx = blockIdx.x * 256 + threadIdx.x;
  int m = idx >> 18;
  int r = idx & 262143;
  int n = r >> 9, k = r & 511;
  size_t si = (size_t)k * 512 + n;
  float v;
  bfloat* dst;
  switch (m) {
    case 0:  v = ldf(We1, 524288 + si, f); dst = WtA; break;
    case 1:  v = ldf(Wu1, 524288 + si, f); dst = WtB; break;
    case 2:  v = ldf(Wu2, si, f);          dst = WtC; break;
    case 3:  v = ldf(We1, si, f);          dst = WtD; break;
    case 4:  v = ldf(We1, 262144 + si, f); dst = WtE; break;
    case 5:  v = ldf(Wu1, si, f);          dst = WtF; break;
    case 6:  v = ldf(Wu1, 262144 + si, f); dst = WtG; break;
    default: v = ldf(Wm, si, f);           dst = WtH; break;
  }
  dst[(size_t)n * 512 + k] = __float2bfloat16(v);
}

// h = node@Wn + b, fp32 + bf16 outputs.
__global__ __launch_bounds__(256) void small_gemm(const void* A, int amode, const void* W,
                                                  size_t woff, const void* bias,
                                                  const int* flag, float* out, bfloat* outb) {
  const int f = *flag;
  const int af = amode ? 1 : f;
  __shared__ float sA[4][512];
  const int t = threadIdx.x;
  const int r0 = blockIdx.x * 4;
  for (int idx = t; idx < 2048; idx += 256)
    sA[idx >> 9][idx & 511] = ldf(A, (size_t)(r0 + (idx >> 9)) * 512 + (idx & 511), af);
  __syncthreads();
  float acc0[4] = {0.f, 0.f, 0.f, 0.f}, acc1[4] = {0.f, 0.f, 0.f, 0.f};
#pragma unroll 4
  for (int k = 0; k < 512; ++k) {
    float w0 = ldf(W, woff + (size_t)k * 512 + t, f);
    float w1 = ldf(W, woff + (size_t)k * 512 + t + 256, f);
#pragma unroll
    for (int r = 0; r < 4; ++r) {
      acc0[r] += sA[r][k] * w0;
      acc1[r] += sA[r][k] * w1;
    }
  }
  float b0 = bias ? ldf(bias, t, f) : 0.f;
  float b1 = bias ? ldf(bias, t + 256, f) : 0.f;
#pragma unroll
  for (int r = 0; r < 4; ++r) {
    float o0 = acc0[r] + b0, o1 = acc1[r] + b1;
    out[(size_t)(r0 + r) * 512 + t] = o0;
    out[(size_t)(r0 + r) * 512 + t + 256] = o1;
    if (outb) {
      outb[(size_t)(r0 + r) * 512 + t] = __float2bfloat16(o0);
      outb[(size_t)(r0 + r) * 512 + t + 256] = __float2bfloat16(o1);
    }
  }
}

// 5 h-GEMMs via MFMA. grid = g(5) x rb(4) x cb(4) = 80 blocks, 128x128 tiles.
// Same 3-deep counted-vmcnt core as k3 (BK=32, 16 iters, swizzle (row>>1)&3).
__global__ __launch_bounds__(256) void fused5_mfma(const bfloat* hb, const bfloat* WtD,
                                                   const bfloat* WtE, const bfloat* WtF,
                                                   const bfloat* WtG, const bfloat* WtH,
                                                   const void* We1b, const void* Wu1b,
                                                   const void* Wmb, const int* flag,
                                                   float* P1, float* Q1, float* P2, float* Q2,
                                                   float* msgv) {
  const int fl = *flag;
  __shared__ __align__(16) char smem[49152];  // A 3x8K [0,24K) | B 3x8K [24K,48K)
  f32x4 acc[4][4];
#pragma unroll
  for (int mi = 0; mi < 4; ++mi)
#pragma unroll
    for (int ni = 0; ni < 4; ++ni) acc[mi][ni] = (f32x4){0.f, 0.f, 0.f, 0.f};

  const int bid = blockIdx.x;
  const int g = bid >> 4, rb = (bid >> 2) & 3, cbv = bid & 3;
  const bfloat* Wt;
  const void* bias = nullptr;
  float* out;
  switch (g) {
    case 0:  Wt = WtD; bias = We1b; out = P1; break;
    case 1:  Wt = WtE; out = Q1; break;
    case 2:  Wt = WtF; bias = Wu1b; out = P2; break;
    case 3:  Wt = WtG; out = Q2; break;
    default: Wt = WtH; bias = Wmb; out = msgv; break;
  }
  const bfloat* Ag = hb + (size_t)rb * 65536;
  const bfloat* Bg = Wt + (size_t)cbv * 65536;

  const int t = threadIdx.x, lane = t & 63, wave = t >> 6;
  const int wrow = wave >> 1, wcol = wave & 1;
  const int l15 = lane & 15, q = lane >> 4;

  const int row0 = t >> 2, p0 = t & 3, g0 = p0 ^ ((row0 >> 1) & 3);
  const int row1 = 64 + row0, g1 = p0 ^ ((row1 >> 1) & 3);
  const char* srcA0 = (const char*)(Ag + (size_t)row0 * 512 + g0 * 8);
  const char* srcA1 = (const char*)(Ag + (size_t)row1 * 512 + g1 * 8);
  const char* srcB0 = (const char*)(Bg + (size_t)row0 * 512 + g0 * 8);
  const char* srcB1 = (const char*)(Bg + (size_t)row1 * 512 + g1 * 8);
  const int dst0 = wave * 1024, dst1 = 4096 + wave * 1024;

  auto stage = [&](int kt2, int sel2) {
    const int koff = kt2 * 64;
    char* dA = smem + sel2 * 8192;
    char* dB = smem + 24576 + sel2 * 8192;
    g2l16(srcA0 + koff, dA + dst0);
    g2l16(srcA1 + koff, dA + dst1);
    g2l16(srcB0 + koff, dB + dst0);
    g2l16(srcB1 + koff, dB + dst1);
  };
  stage(0, 0);
  stage(1, 1);

  const int swz = (q ^ ((l15 >> 1) & 3)) * 16;
  const int fA = (wrow * 64 + l15) * 64 + swz;
  const int fB = (wcol * 64 + l15) * 64 + swz;

#pragma unroll
  for (int kt = 0; kt < 16; ++kt) {
    if (kt < 15) asm volatile("s_waitcnt vmcnt(4)" ::: "memory");
    else         asm volatile("s_waitcnt vmcnt(0)" ::: "memory");
    __builtin_amdgcn_s_barrier();
    if (kt < 14) stage(kt + 2, (kt + 2) % 3);
    const char* A = smem + (kt % 3) * 8192;
    const char* B = smem + 24576 + (kt % 3) * 8192;
    bf16x8 afr[4], bfr[4];
#pragma unroll
    for (int mi = 0; mi < 4; ++mi) afr[mi] = *(const bf16x8*)(A + fA + mi * 1024);
#pragma unroll
    for (int ni = 0; ni < 4; ++ni) bfr[ni] = *(const bf16x8*)(B + fB + ni * 1024);
#pragma unroll
    for (int mi = 0; mi < 4; ++mi)
#pragma unroll
      for (int ni = 0; ni < 4; ++ni)
        acc[mi][ni] =
            __builtin_amdgcn_mfma_f32_16x16x32_bf16(afr[mi], bfr[ni], acc[mi][ni], 0, 0, 0);
  }

  float bv[4];
#pragma unroll
  for (int ni = 0; ni < 4; ++ni)
    bv[ni] = bias ? ldf(bias, (size_t)cbv * 128 + wcol * 64 + ni * 16 + l15, fl) : 0.f;
#pragma unroll
  for (int mi = 0; mi < 4; ++mi)
#pragma unroll
    for (int rr = 0; rr < 4; ++rr) {
      const int j = wrow * 64 + mi * 16 + q * 4 + rr;
#pragma unroll
      for (int ni = 0; ni < 4; ++ni) {
        const int cc = wcol * 64 + ni * 16 + l15;
        out[(size_t)(rb * 128 + j) * 512 + cbv * 128 + cc] = acc[mi][ni][rr] + bv[ni];
      }
    }
}

// K3 (paired): block (bm, cb) computes attn col-block AND u col-block off one
// staged E tile. BK=32, 16 iters, 3-deep vmcnt(6) pipeline, 32 MFMA/iter.
// LDS 76KB: A 3x8K [0,24K) | B 3x16K [24K,72K) | We2 [72K,76K).
// Epilogues reuse [0,32K) as the 128x128 bf16 swizzled image (u first, attn second).
__global__ __launch_bounds__(256) void k3_edge_mlp(const void* E, const bfloat* WtA,
                                                   const bfloat* WtB, const float* P1,
                                                   const float* Q1, const float* P2,
                                                   const float* Q2, const void* We2,
                                                   const int* flag, float* logits4, void* dout) {
  const int f = *flag;
  __shared__ __align__(16) char smem[77824];
  f32x4 accA[4][4], accU[4][4];
#pragma unroll
  for (int mi = 0; mi < 4; ++mi)
#pragma unroll
    for (int ni = 0; ni < 4; ++ni) {
      accA[mi][ni] = (f32x4){0.f, 0.f, 0.f, 0.f};
      accU[mi][ni] = (f32x4){0.f, 0.f, 0.f, 0.f};
    }

  const int idx0 = blockIdx.x;                  // 0..2047
  const int bm = (idx0 >> 5) * 8 + (idx0 & 7);  // 0..511, XCD = bm&7
  const int cb = (idx0 >> 3) & 3;               // col-block 0..3
  const int blockcol = cb * 128;
  const bfloat* BgA = WtA + (size_t)cb * 65536;
  const bfloat* BgU = WtB + (size_t)cb * 65536;
  const bfloat* Eb = (const bfloat*)E;
  const char* eb = (const char*)dout + 1048576;

  const int t = threadIdx.x, lane = t & 63, wave = t >> 6;
  const int wrow = wave >> 1, wcol = wave & 1;
  const int l15 = lane & 15, q = lane >> 4;

  // We2 tile first (its loads drain via their own ds_write waits, keeping the
  // vmcnt ledger = stage loads only by loop entry)
  for (int idx = t; idx < 2048; idx += 256) {
    const int n = idx >> 7, k = idx & 127;
    float v = (n < 8) ? ldf(We2, (size_t)(blockcol + k) * 8 + n, f) : 0.f;
    *(bfloat*)(smem + 73728 + (size_t)n * 256 + (((k >> 3) ^ n) * 16) + (k & 7) * 2) =
        __float2bfloat16(v);
  }

  // A staging sources (2 loads), swizzle (row>>1)&3
  const int row0 = t >> 2, p0 = t & 3, g0 = p0 ^ ((row0 >> 1) & 3);
  const int row1 = 64 + row0, g1 = p0 ^ ((row1 >> 1) & 3);
  const char* srcA0;
  const char* srcA1;
  const int gr0 = bm * 128 + row0, gr1 = gr0 + 64;
  if (f) {
    srcA0 = eb + (size_t)(gr0 >> 6) * 131072 + (size_t)(gr0 & 63) * 1024 + (size_t)g0 * 16;
    srcA1 = eb + (size_t)(gr1 >> 6) * 131072 + (size_t)(gr1 & 63) * 1024 + (size_t)g1 * 16;
  } else {
    srcA0 = (const char*)Eb + ((size_t)gr0 * 512 + g0 * 8) * 2;
    srcA1 = (const char*)Eb + ((size_t)gr1 * 512 + g1 * 8) * 2;
  }
  const int dstA0 = wave * 1024, dstA1 = 4096 + wave * 1024;

  // B staging: 4 loads covering 256 rows (128 attn + 128 u)
  const char* srcB[4];
  int dstB[4];
#pragma unroll
  for (int c = 0; c < 4; ++c) {
    const int idx = c * 256 + t;
    const int row = idx >> 2, p = idx & 3, gg = p ^ ((row >> 1) & 3);
    const bfloat* base =
        (row < 128) ? (BgA + (size_t)row * 512) : (BgU + (size_t)(row - 128) * 512);
    srcB[c] = (const char*)base + gg * 16;
    dstB[c] = (c * 256 + wave * 64) * 16;
  }

  auto stage = [&](int kt2, int sel2) {
    const int koff = kt2 * 64;
    char* dA = smem + sel2 * 8192;
    char* dB = smem + 24576 + sel2 * 16384;
    g2l16(srcA0 + koff, dA + dstA0);
    g2l16(srcA1 + koff, dA + dstA1);
#pragma unroll
    for (int c = 0; c < 4; ++c) g2l16(srcB[c] + koff, dB + dstB[c]);
  };
  stage(0, 0);
  stage(1, 1);

  const int swz = (q ^ ((l15 >> 1) & 3)) * 16;
  const int fA = (wrow * 64 + l15) * 64 + swz;
  const int fB = (wcol * 64 + l15) * 64 + swz;

#pragma unroll
  for (int kt = 0; kt < 16; ++kt) {
    if (kt < 15) asm volatile("s_waitcnt vmcnt(6)" ::: "memory");
    else         asm volatile("s_waitcnt vmcnt(0)" ::: "memory");
    __builtin_amdgcn_s_barrier();
    if (kt < 14) stage(kt + 2, (kt + 2) % 3);
    const char* A = smem + (kt % 3) * 8192;
    const char* B = smem + 24576 + (kt % 3) * 16384;
    bf16x8 afr[4], bfrA[4], bfrU[4];
#pragma unroll
    for (int mi = 0; mi < 4; ++mi) afr[mi] = *(const bf16x8*)(A + fA + mi * 1024);
#pragma unroll
    for (int ni = 0; ni < 4; ++ni) bfrA[ni] = *(const bf16x8*)(B + fB + ni * 1024);
#pragma unroll
    for (int mi = 0; mi < 4; ++mi)
#pragma unroll
      for (int ni = 0; ni < 4; ++ni)
        accA[mi][ni] =
            __builtin_amdgcn_mfma_f32_16x16x32_bf16(afr[mi], bfrA[ni], accA[mi][ni], 0, 0, 0);
#pragma unroll
    for (int ni = 0; ni < 4; ++ni) bfrU[ni] = *(const bf16x8*)(B + 8192 + fB + ni * 1024);
#pragma unroll
    for (int mi = 0; mi < 4; ++mi)
#pragma unroll
      for (int ni = 0; ni < 4; ++ni)
        accU[mi][ni] =
            __builtin_amdgcn_mfma_f32_16x16x32_bf16(afr[mi], bfrU[ni], accU[mi][ni], 0, 0, 0);
  }

  const int b = bm >> 7;
  float pv1[4], pv2[4];
#pragma unroll
  for (int ni = 0; ni < 4; ++ni) {
    const size_t o = (size_t)bm * 512 + blockcol + wcol * 64 + ni * 16 + l15;
    pv1[ni] = P1[o];
    pv2[ni] = P2[o];
  }
  __syncthreads();  // last tile's frag reads retired before smem reuse as image

  // ---- u path: gelu image -> coalesced global store ----
#pragma unroll
  for (int mi = 0; mi < 4; ++mi)
#pragma unroll
    for (int rr = 0; rr < 4; ++rr) {
      const int j = wrow * 64 + mi * 16 + q * 4 + rr;
#pragma unroll
      for (int ni = 0; ni < 4; ++ni) {
        const int cc = wcol * 64 + ni * 16 + l15;
        const int c = blockcol + cc;
        float x = accU[mi][ni][rr] + pv2[ni] + Q2[((size_t)b * 128 + j) * 512 + c];
        *(bfloat*)(smem + (size_t)j * 256 + (((cc >> 3) ^ (j & 15)) * 16) + (cc & 7) * 2) =
            __float2bfloat16(gelu_f(x));
      }
    }
  __syncthreads();
  {
    char* ubase = (char*)dout + (f ? (1048576 + 65536) : 524288);
    const size_t blkstride = f ? 131072 : 65536;
#pragma unroll
    for (int rd = 0; rd < 8; ++rd) {
      const int j = rd * 16 + (t >> 4);
      const int ch = t & 15;
      f32x4 v = *(const f32x4*)(smem + (size_t)j * 256 + ((ch ^ (j & 15)) * 16));
      const size_t m = (size_t)bm * 128 + j;
      *(f32x4*)(ubase + (m >> 6) * blkstride + (m & 63) * 1024 + (size_t)blockcol * 2 +
                (size_t)ch * 16) = v;
    }
  }
  __syncthreads();  // u-store reads done before attn image overwrite

  // ---- attn path: lrelu image -> MFMA vs We2 tile -> logits4 partial ----
#pragma unroll
  for (int mi = 0; mi < 4; ++mi)
#pragma unroll
    for (int rr = 0; rr < 4; ++rr) {
      const int j = wrow * 64 + mi * 16 + q * 4 + rr;
#pragma unroll
      for (int ni = 0; ni < 4; ++ni) {
        const int cc = wcol * 64 + ni * 16 + l15;
        const int c = blockcol + cc;
        float x = accA[mi][ni][rr] + pv1[ni] + Q1[((size_t)b * 128 + j) * 512 + c];
        float e4 = (x >= 0.f) ? x : 0.2f * x;
        *(bfloat*)(smem + (size_t)j * 256 + (((cc >> 3) ^ (j & 15)) * 16) + (cc & 7) * 2) =
            __float2bfloat16(e4);
      }
    }
  __syncthreads();
  {
    f32x4 acc2[2];
    acc2[0] = (f32x4){0.f, 0.f, 0.f, 0.f};
    acc2[1] = (f32x4){0.f, 0.f, 0.f, 0.f};
    const int jb = wave * 32;
#pragma unroll
    for (int ks = 0; ks < 4; ++ks) {
      const int gA = ((ks * 4 + q) ^ l15) * 16;
      bf16x8 a0 = *(const bf16x8*)(smem + (size_t)(jb + l15) * 256 + gA);
      bf16x8 a1 = *(const bf16x8*)(smem + (size_t)(jb + 16 + l15) * 256 + gA);
      bf16x8 bb = *(const bf16x8*)(smem + 73728 + (size_t)l15 * 256 + gA);
      acc2[0] = __builtin_amdgcn_mfma_f32_16x16x32_bf16(a0, bb, acc2[0], 0, 0, 0);
      acc2[1] = __builtin_amdgcn_mfma_f32_16x16x32_bf16(a1, bb, acc2[1], 0, 0, 0);
    }
#pragma unroll
    for (int mi2 = 0; mi2 < 2; ++mi2)
#pragma unroll
      for (int rr = 0; rr < 4; ++rr) {
        if (l15 < 8) {
          const int j = jb + mi2 * 16 + q * 4 + rr;
          logits4[(((size_t)cb * 512 + bm) * 128 + j) * 8 + l15] = acc2[mi2][rr];
        }
      }
  }
}

// K6: out = E + u@Wu2 + b. One block owns one 64-row chunk; BK=32, 16 K-iters.
// 3-deep counted-vmcnt pipeline. LDS 108KB: A 3x4KB [0,12K), B 3x32KB.
__global__ __launch_bounds__(512) void k6_edge_out(const bfloat* WtC, const void* Wu2b,
                                                   const void* E, const int* flag, void* dout) {
  const int f = *flag;
  __shared__ __align__(16) char smem[110592];
  f32x4 acc[2][8];
#pragma unroll
  for (int mi = 0; mi < 2; ++mi)
#pragma unroll
    for (int ni = 0; ni < 8; ++ni) acc[mi][ni] = (f32x4){0.f, 0.f, 0.f, 0.f};

  const int e = blockIdx.x & 7;
  const int x = blockIdx.x >> 3;
  const int bm = 2 * e + 16 * (x >> 1) + (x & 1);  // chunk 0..1023, XCD = (bm>>1)&7 == e
  const int t = threadIdx.x;
  const int lane = t & 63;
  const int wave = t >> 6;
  const int wm = wave >> 2, wn = wave & 3;
  const int l15 = lane & 15;
  const int q = lane >> 4;
  const size_t r0 = (size_t)bm * 64;
  const char* ua = (const char*)dout +
                   (f ? (1048576 + (size_t)bm * 131072 + 65536) : (524288 + (size_t)bm * 65536));

  const int iA = t & 255;
  const int rowA = iA >> 2, pA = iA & 3, gA = pA ^ ((rowA >> 1) & 3);
  const char* srcA = ua + (size_t)rowA * 1024 + (size_t)gA * 16;
  const int dstA = (wave & 3) * 1024;
  const char* srcB[4];
  int dstB[4];
#pragma unroll
  for (int c = 0; c < 4; ++c) {
    const int idx = c * 512 + t;
    const int row = idx >> 2, p = idx & 3, g = p ^ ((row >> 1) & 3);
    srcB[c] = (const char*)WtC + ((size_t)row * 512 + g * 8) * 2;
    dstB[c] = (c * 512 + wave * 64) * 16;
  }

  auto stage = [&](int kt2, int sel2) {
    const int koff = kt2 * 64;
    char* dA = smem + sel2 * 4096;
    char* dB = smem + 12288 + sel2 * 32768;
    g2l16(srcA + koff, dA + dstA);
#pragma unroll
    for (int c = 0; c < 4; ++c) g2l16(srcB[c] + koff, dB + dstB[c]);
  };

  stage(0, 0);
  stage(1, 1);

  const int swz = (q ^ ((l15 >> 1) & 3)) * 16;
  const int fAo = (wm * 32 + l15) * 64 + swz;
  const int fBo = (wn * 128 + l15) * 64 + swz;

#pragma unroll
  for (int kt = 0; kt < 16; ++kt) {
    if (kt < 15) asm volatile("s_waitcnt vmcnt(5)" ::: "memory");
    else         asm volatile("s_waitcnt vmcnt(0)" ::: "memory");
    __builtin_amdgcn_s_barrier();
    if (kt < 14) stage(kt + 2, (kt + 2) % 3);
    const char* sA = smem + (kt % 3) * 4096;
    const char* sB = smem + 12288 + (kt % 3) * 32768;
    bf16x8 afr[2], bfr[8];
#pragma unroll
    for (int mi = 0; mi < 2; ++mi) afr[mi] = *(const bf16x8*)(sA + fAo + mi * 1024);
#pragma unroll
    for (int ni = 0; ni < 8; ++ni) bfr[ni] = *(const bf16x8*)(sB + fBo + ni * 1024);
#pragma unroll
    for (int mi = 0; mi < 2; ++mi)
#pragma unroll
      for (int ni = 0; ni < 8; ++ni)
        acc[mi][ni] = __builtin_amdgcn_mfma_f32_16x16x32_bf16(afr[mi], bfr[ni], acc[mi][ni], 0, 0, 0);
  }
  float wb[8];
#pragma unroll
  for (int ni = 0; ni < 8; ++ni) wb[ni] = ldf(Wu2b, wn * 128 + ni * 16 + l15, f);
  const bfloat* eres = (const bfloat*)((const char*)dout + 1048576 + (size_t)bm * 131072);
#pragma unroll
  for (int mi = 0; mi < 2; ++mi)
#pragma unroll
    for (int rr = 0; rr < 4; ++rr) {
      const int j = wm * 32 + mi * 16 + q * 4 + rr;
#pragma unroll
      for (int ni = 0; ni < 8; ++ni) {
        const int c = wn * 128 + ni * 16 + l15;
        float r = f ? __bfloat162float(eres[(size_t)j * 512 + c])
                    : __bfloat162float(((const bfloat*)E)[(r0 + j) * 512 + c]);
        acc[mi][ni][rr] += wb[ni] + r;
      }
    }
  __syncthreads();  // all residual reads drained before overwriting the range
#pragma unroll
  for (int mi = 0; mi < 2; ++mi)
#pragma unroll
    for (int rr = 0; rr < 4; ++rr) {
      const int j = wm * 32 + mi * 16 + q * 4 + rr;
      const size_t row = r0 + j;
#pragma unroll
      for (int ni = 0; ni < 8; ++ni) {
        const int c = wn * 128 + ni * 16 + l15;
        stf(dout, 262144 + row * 512 + c, acc[mi][ni][rr], f);
      }
    }
}

// shfl_xor-based; 8 h's reduced simultaneously, 3 barriers total.
__global__ __launch_bounds__(128) void softmax_mean(const float* logits4, const void* adj,
                                                    const int* flag, float* amean) {
  const int f = *flag;
  const int bi = blockIdx.x;
  const int j = threadIdx.x;   // 0..127
  const int wv = j >> 6;
  __shared__ float sred[2][8];
  f32x4 v0 = (f32x4){0.f, 0.f, 0.f, 0.f}, v1 = (f32x4){0.f, 0.f, 0.f, 0.f};
#pragma unroll
  for (int s = 0; s < 4; ++s) {
    const float* p = logits4 + (((size_t)s * 512 + bi) * 128 + j) * 8;
    v0 += *(const f32x4*)p;
    v1 += *(const f32x4*)(p + 4);
  }
  float xv[8], m[8];
#pragma unroll
  for (int k = 0; k < 4; ++k) { xv[k] = v0[k]; xv[4 + k] = v1[k]; }
#pragma unroll
  for (int h = 0; h < 8; ++h) m[h] = xv[h];
#pragma unroll
  for (int o = 1; o < 64; o <<= 1)
#pragma unroll
    for (int h = 0; h < 8; ++h) m[h] = fmaxf(m[h], __shfl_xor(m[h], o));
  if ((j & 63) == 0) {
#pragma unroll
    for (int h = 0; h < 8; ++h) sred[wv][h] = m[h];
  }
  __syncthreads();
  float ex[8], s8[8];
#pragma unroll
  for (int h = 0; h < 8; ++h) {
    float mx = fmaxf(sred[0][h], sred[1][h]);
    ex[h] = __expf(xv[h] - mx);
    s8[h] = ex[h];
  }
#pragma unroll
  for (int o = 1; o < 64; o <<= 1)
#pragma unroll
    for (int h = 0; h < 8; ++h) s8[h] += __shfl_xor(s8[h], o);
  __syncthreads();
  if ((j & 63) == 0) {
#pragma unroll
    for (int h = 0; h < 8; ++h) sred[wv][h] = s8[h];
  }
  __syncthreads();
  float macc = 0.f;
#pragma unroll
  for (int h = 0; h < 8; ++h) macc += ex[h] / (sred[0][h] + sred[1][h]);
  amean[(size_t)bi * 128 + j] = macc * 0.125f * ldf(adj, (size_t)bi * 128 + j, f);
}

// fused aggregate + Wo + LayerNorm. r3: 4 rows/block (128 blocks), shfl LN.
__global__ __launch_bounds__(256) void node_fused(const float* amean, const float* msg,
                                                  const void* Wo, const void* Wob,
                                                  const void* node, const void* lng,
                                                  const void* lnb, const int* flag, void* dout) {
  const int f = *flag;
  const int r0 = blockIdx.x * 4;     // rows r0..r0+3, same batch (128%4==0)
  const int b = r0 >> 7;
  const int t = threadIdx.x;
  const int lane = t & 63, wave = t >> 6;
  __shared__ float am[512];
  __shared__ float sAgg[4][512];
  __shared__ float sw[4][4];
  __shared__ float sw2[4][4];
  am[t] = amean[(size_t)r0 * 128 + t];
  am[t + 256] = amean[(size_t)r0 * 128 + t + 256];
  __syncthreads();
  float a0[4] = {0.f, 0.f, 0.f, 0.f}, a1[4] = {0.f, 0.f, 0.f, 0.f};
#pragma unroll 2
  for (int jj = 0; jj < 128; ++jj) {
    const float* mr = msg + ((size_t)b * 128 + jj) * 512;
    float m0 = mr[t], m1 = mr[t + 256];
#pragma unroll
    for (int r = 0; r < 4; ++r) {
      a0[r] += am[r * 128 + jj] * m0;
      a1[r] += am[r * 128 + jj] * m1;
    }
  }
#pragma unroll
  for (int r = 0; r < 4; ++r) { sAgg[r][t] = a0[r]; sAgg[r][t + 256] = a1[r]; }
  __syncthreads();
  float v0[4] = {0.f, 0.f, 0.f, 0.f}, v1[4] = {0.f, 0.f, 0.f, 0.f};
  if (f) {
    const float* W = (const float*)Wo;
#pragma unroll 2
    for (int k = 0; k < 512; ++k) {
      float w0 = W[(size_t)k * 512 + t], w1 = W[(size_t)k * 512 + t + 256];
#pragma unroll
      for (int r = 0; r < 4; ++r) { v0[r] += sAgg[r][k] * w0; v1[r] += sAgg[r][k] * w1; }
    }
  } else {
    const bfloat* W = (const bfloat*)Wo;
#pragma unroll 2
    for (int k = 0; k < 512; ++k) {
      float w0 = __bfloat162float(W[(size_t)k * 512 + t]);
      float w1 = __bfloat162float(W[(size_t)k * 512 + t + 256]);
#pragma unroll
      for (int r = 0; r < 4; ++r) { v0[r] += sAgg[r][k] * w0; v1[r] += sAgg[r][k] * w1; }
    }
  }
  float wob0 = ldf(Wob, t, f), wob1 = ldf(Wob, t + 256, f);
#pragma unroll
  for (int r = 0; r < 4; ++r) {
    v0[r] += wob0 + ldf(node, (size_t)(r0 + r) * 512 + t, f);
    v1[r] += wob1 + ldf(node, (size_t)(r0 + r) * 512 + t + 256, f);
  }
  float s[4];
#pragma unroll
  for (int r = 0; r < 4; ++r) s[r] = v0[r] + v1[r];
#pragma unroll
  for (int o = 1; o < 64; o <<= 1)
#pragma unroll
    for (int r = 0; r < 4; ++r) s[r] += __shfl_xor(s[r], o);
  if (lane == 0) {
#pragma unroll
    for (int r = 0; r < 4; ++r) sw[wave][r] = s[r];
  }
  __syncthreads();
  float mean[4];
#pragma unroll
  for (int r = 0; r < 4; ++r)
    mean[r] = (sw[0][r] + sw[1][r] + sw[2][r] + sw[3][r]) * (1.f / 512.f);
#pragma unroll
  for (int r = 0; r < 4; ++r) {
    float d0 = v0[r] - mean[r], d1 = v1[r] - mean[r];
    s[r] = d0 * d0 + d1 * d1;
  }
#pragma unroll
  for (int o = 1; o < 64; o <<= 1)
#pragma unroll
    for (int r = 0; r < 4; ++r) s[r] += __shfl_xor(s[r], o);
  if (lane == 0) {
#pragma unroll
    for (int r = 0; r < 4; ++r) sw2[wave][r] = s[r];
  }
  __syncthreads();
  float g0v = ldf(lng, t, f), g1v = ldf(lng, t + 256, f);
  float b0v = ldf(lnb, t, f), b1v = ldf(lnb, t + 256, f);
#pragma unroll
  for (int r = 0; r < 4; ++r) {
    float var = (sw2[0][r] + sw2[1][r] + sw2[2][r] + sw2[3][r]) * (1.f / 512.f);
    float inv = rsqrtf(var + 1e-5f);
    stf(dout, (size_t)(r0 + r) * 512 + t, (v0[r] - mean[r]) * inv * g0v + b0v, f);
    stf(dout, (size_t)(r0 + r) * 512 + t + 256, (v1[r] - mean[r]) * inv * g1v + b1v, f);
  }
}

extern "C" void kernel_launch(void* const* d_in, const int* in_sizes, int n_in, void* d_out,
                              int out_size, void* d_ws, size_t ws_size, hipStream_t stream) {
  (void)in_sizes; (void)n_in; (void)out_size; (void)ws_size;
  const void* node = d_in[0];
  const void* edge = d_in[1];
  const void* adj = d_in[2];
  const void* Wn_w = d_in[3];
  const void* Wn_b = d_in[4];
  const void* We1_w = d_in[5];
  const void* We1_b = d_in[6];
  const void* We2_w = d_in[7];
  // d_in[8] = We2_b: constant over j -> cancels in softmax, unused.
  const void* Wm_w = d_in[9];
  const void* Wm_b = d_in[10];
  const void* Wu1_w = d_in[11];
  const void* Wu1_b = d_in[12];
  const void* Wu2_w = d_in[13];
  const void* Wu2_b = d_in[14];
  const void* Wo_w = d_in[15];
  const void* Wo_b = d_in[16];
  const void* ln_g = d_in[17];
  const void* ln_b = d_in[18];

  char* w = (char*)d_ws;
  int* flag = (int*)w;        w += 256;
  float* h = (float*)w;       w += 262144 * 4;
  float* P1 = (float*)w;      w += 262144 * 4;
  float* Q1 = (float*)w;      w += 262144 * 4;
  float* P2 = (float*)w;      w += 262144 * 4;
  float* Q2 = (float*)w;      w += 262144 * 4;
  float* msg = (float*)w;     w += 262144 * 4;
  float* logits4 = (float*)w; w += (size_t)4 * 524288 * 4;  // [4][512][128][8] fp32 = 8MB
  float* amean = (float*)w;   w += 65536 * 4;
  bfloat* WtA = (bfloat*)w;   w += 262144 * 2;
  bfloat* WtB = (bfloat*)w;   w += 262144 * 2;
  bfloat* WtC = (bfloat*)w;   w += 262144 * 2;
  bfloat* WtD = (bfloat*)w;   w += 262144 * 2;
  bfloat* WtE = (bfloat*)w;   w += 262144 * 2;
  bfloat* WtF = (bfloat*)w;   w += 262144 * 2;
  bfloat* WtG = (bfloat*)w;   w += 262144 * 2;
  bfloat* WtH = (bfloat*)w;   w += 262144 * 2;
  bfloat* hb = (bfloat*)w;    w += 262144 * 2;
  // total ~18.3MB

  detect_dtype<<<1, 256, 0, stream>>>((const unsigned short*)node, flag);
  cvt_edge<<<16384, 256, 0, stream>>>((const float*)edge, flag, d_out);
  transpose3<<<8192, 256, 0, stream>>>(We1_w, Wu1_w, Wu2_w, Wm_w, flag, WtA, WtB, WtC,
                                       WtD, WtE, WtF, WtG, WtH);
  small_gemm<<<128, 256, 0, stream>>>(node, 0, Wn_w, 0, Wn_b, flag, h, hb);
  fused5_mfma<<<80, 256, 0, stream>>>(hb, WtD, WtE, WtF, WtG, WtH, We1_b, Wu1_b, Wm_b, flag,
                                      P1, Q1, P2, Q2, msg);
  k3_edge_mlp<<<2048, 256, 0, stream>>>(edge, WtA, WtB, P1, Q1, P2, Q2, We2_w, flag,
                                        logits4, d_out);
  softmax_mean<<<512, 128, 0, stream>>>(logits4, adj, flag, amean);
  node_fused<<<128, 256, 0, stream>>>(amean, msg, Wo_w, Wo_b, node, ln_g, ln_b, flag, d_out);
  k6_edge_out<<<1024, 512, 0, stream>>>(WtC, Wu2_b, edge, flag, d_out);
}

// Round 4
// 737.607 us; speedup vs baseline: 1.1166x; 1.1166x over previous
//
#include <hip/hip_runtime.h>
#include <hip/hip_bf16.h>

// GraphConvLayer B=4,N=128,D=512,H=8. Input dtype (bf16|fp32) runtime-detected
// -> flag in ws; output dtype follows input dtype.
// f==1: E pre-converted to bf16 into d_out's outE region, chunk-layout:
//   chunk c (64 rows) at [1048576 + c*131072, +131072): [Ebf16 64x1024B | u 64x1024B].
// u placement (r4): if ws_size permits, u goes to u_ws (linear 1024B rows) for BOTH
//   f modes -> k6_ws is a clean 128x128-tile GEMM (no in-place aliasing), residual
//   from original E, 48KB LDS, 3 blocks/CU. Fallback (small ws): r1 chunk k6.
// k3 (r2-proven): BK=32, 16 iters, 3-deep vmcnt(4) pipeline, LDS 52KB, swizzle
//   (row>>1)&3 (bank-conflict-free), MFMA attn epilogue vs We2 tile.
// Occupancy lesson (r3): this family is latency-bound; 3 blocks/CU beats
//   2 blocks/CU with 2x MFMA/iter. Keep LDS <= ~52KB per block.
// XCD-locality: cvt_edge/k3/k6 grids swizzled so row-block rb is produced and
//   consumed on XCD rb&7.

typedef __bf16  bf16x8 __attribute__((ext_vector_type(8)));
typedef float   f32x4  __attribute__((ext_vector_type(4)));
typedef __hip_bfloat16 bfloat;

#define AS1 __attribute__((address_space(1)))
#define AS3 __attribute__((address_space(3)))

__device__ __forceinline__ void g2l16(const void* g, void* l) {
  __builtin_amdgcn_global_load_lds((AS1 void*)g, (AS3 void*)l, 16, 0, 0);
}

__device__ __forceinline__ float ldf(const void* p, size_t i, int f) {
  return f ? ((const float*)p)[i] : __bfloat162float(((const bfloat*)p)[i]);
}
__device__ __forceinline__ void stf(void* p, size_t i, float v, int f) {
  if (f) ((float*)p)[i] = v;
  else   ((bfloat*)p)[i] = __float2bfloat16(v);
}

// tanh-form GELU (max abs err ~3e-4 vs exact erf form; well under threshold)
__device__ __forceinline__ float gelu_f(float x) {
  float y = 0.7978845608028654f * (x + 0.044715f * x * x * x);
  float e = __expf(2.0f * y);
  float t = 1.0f - 2.0f / (e + 1.0f);
  return 0.5f * x * (1.0f + t);
}

__global__ __launch_bounds__(256) void detect_dtype(const unsigned short* nu, int* flag) {
  __shared__ int bad;
  if (threadIdx.x == 0) bad = 0;
  __syncthreads();
  int local = 0;
  for (int i = threadIdx.x; i < 4096; i += 256) {
    int ex = (nu[i] >> 7) & 0xFF;
    if (ex >= 0xC0) local = 1;
  }
  if (local) atomicOr(&bad, 1);
  __syncthreads();
  if (threadIdx.x == 0) *flag = bad;
}

// f==1 only: E fp32 -> bf16 chunk layout in dout. Grid 16384, XCD-aligned.
__global__ __launch_bounds__(256) void cvt_edge(const float* E, const int* flag, void* dout) {
  if (*flag == 0) return;
  const int e = blockIdx.x & 7;
  const int x = blockIdx.x >> 3;          // 0..2047
  const int m = x >> 5;                   // 0..63
  const int h = (x >> 4) & 1;
  const int s = x & 15;                   // 16 blocks per chunk
  const int c = 2 * e + 16 * m + h;       // chunk 0..1023
  const int t = threadIdx.x;
  const int rloc = s * 4 + (t >> 6);      // row within chunk 0..63
  const int c8 = t & 63;
  const float* src = E + ((size_t)c * 64 + rloc) * 512 + (size_t)c8 * 8;
  f32x4 lo = *(const f32x4*)src;
  f32x4 hi = *(const f32x4*)(src + 4);
  bf16x8 v;
  v[0] = (__bf16)lo[0]; v[1] = (__bf16)lo[1]; v[2] = (__bf16)lo[2]; v[3] = (__bf16)lo[3];
  v[4] = (__bf16)hi[0]; v[5] = (__bf16)hi[1]; v[6] = (__bf16)hi[2]; v[7] = (__bf16)hi[3];
  char* eb = (char*)dout + 1048576;
  *(bf16x8*)(eb + (size_t)c * 131072 + (size_t)rloc * 1024 + (size_t)c8 * 16) = v;
}

// 8 transposed bf16 weight copies (n-major [n][k]) via LDS 64x64 tiles:
// both global read and write coalesced. Grid 8*64 = 512 blocks.
__global__ __launch_bounds__(256) void transpose8(const void* We1, const void* Wu1,
                                                  const void* Wu2, const void* Wm,
                                                  const int* flag,
                                                  bfloat* WtA, bfloat* WtB, bfloat* WtC,
                                                  bfloat* WtD, bfloat* WtE, bfloat* WtF,
                                                  bfloat* WtG, bfloat* WtH) {
  const int f = *flag;
  __shared__ float sT[64][65];
  const int m = blockIdx.x >> 6;
  const int tile = blockIdx.x & 63;
  const int k0 = (tile >> 3) * 64, n0 = (tile & 7) * 64;
  const void* src;
  size_t woff = 0;
  bfloat* dst;
  switch (m) {
    case 0:  src = We1; woff = 524288; dst = WtA; break;
    case 1:  src = Wu1; woff = 524288; dst = WtB; break;
    case 2:  src = Wu2; dst = WtC; break;
    case 3:  src = We1; dst = WtD; break;
    case 4:  src = We1; woff = 262144; dst = WtE; break;
    case 5:  src = Wu1; dst = WtF; break;
    case 6:  src = Wu1; woff = 262144; dst = WtG; break;
    default: src = Wm; dst = WtH; break;
  }
  const int t = threadIdx.x;
#pragma unroll
  for (int p = 0; p < 4; ++p) {
    const int r = p * 16 + (t >> 4);       // k-row 0..63
    const int cs = (t & 15) * 4;           // n-col segment
    const size_t base = woff + (size_t)(k0 + r) * 512 + n0 + cs;
#pragma unroll
    for (int i = 0; i < 4; ++i) sT[r][cs + i] = ldf(src, base + i, f);
  }
  __syncthreads();
#pragma unroll
  for (int p = 0; p < 2; ++p) {
    const int n = p * 32 + (t >> 3);       // 0..63
    const int ks = (t & 7) * 8;
    bf16x8 v;
#pragma unroll
    for (int i = 0; i < 8; ++i) v[i] = (__bf16)sT[ks + i][n];
    *(bf16x8*)(dst + (size_t)(n0 + n) * 512 + k0 + ks) = v;
  }
}

// h = node@Wn + b, fp32 + bf16 outputs.
__global__ __launch_bounds__(256) void small_gemm(const void* A, int amode, const void* W,
                                                  size_t woff, const void* bias,
                                                  const int* flag, float* out, bfloat* outb) {
  const int f = *flag;
  const int af = amode ? 1 : f;
  __shared__ float sA[4][512];
  const int t = threadIdx.x;
  const int r0 = blockIdx.x * 4;
  for (int idx = t; idx < 2048; idx += 256)
    sA[idx >> 9][idx & 511] = ldf(A, (size_t)(r0 + (idx >> 9)) * 512 + (idx & 511), af);
  __syncthreads();
  float acc0[4] = {0.f, 0.f, 0.f, 0.f}, acc1[4] = {0.f, 0.f, 0.f, 0.f};
#pragma unroll 4
  for (int k = 0; k < 512; ++k) {
    float w0 = ldf(W, woff + (size_t)k * 512 + t, f);
    float w1 = ldf(W, woff + (size_t)k * 512 + t + 256, f);
#pragma unroll
    for (int r = 0; r < 4; ++r) {
      acc0[r] += sA[r][k] * w0;
      acc1[r] += sA[r][k] * w1;
    }
  }
  float b0 = bias ? ldf(bias, t, f) : 0.f;
  float b1 = bias ? ldf(bias, t + 256, f) : 0.f;
#pragma unroll
  for (int r = 0; r < 4; ++r) {
    float o0 = acc0[r] + b0, o1 = acc1[r] + b1;
    out[(size_t)(r0 + r) * 512 + t] = o0;
    out[(size_t)(r0 + r) * 512 + t + 256] = o1;
    if (outb) {
      outb[(size_t)(r0 + r) * 512 + t] = __float2bfloat16(o0);
      outb[(size_t)(r0 + r) * 512 + t + 256] = __float2bfloat16(o1);
    }
  }
}

// 5 h-GEMMs via MFMA. grid = g(5) x rb(4) x cb(4) = 80 blocks, 128x128 tiles.
__global__ __launch_bounds__(256) void fused5_mfma(const bfloat* hb, const bfloat* WtD,
                                                   const bfloat* WtE, const bfloat* WtF,
                                                   const bfloat* WtG, const bfloat* WtH,
                                                   const void* We1b, const void* Wu1b,
                                                   const void* Wmb, const int* flag,
                                                   float* P1, float* Q1, float* P2, float* Q2,
                                                   float* msgv) {
  const int fl = *flag;
  __shared__ __align__(16) char smem[49152];  // A 3x8K [0,24K) | B 3x8K [24K,48K)
  f32x4 acc[4][4];
#pragma unroll
  for (int mi = 0; mi < 4; ++mi)
#pragma unroll
    for (int ni = 0; ni < 4; ++ni) acc[mi][ni] = (f32x4){0.f, 0.f, 0.f, 0.f};

  const int bid = blockIdx.x;
  const int g = bid >> 4, rb = (bid >> 2) & 3, cbv = bid & 3;
  const bfloat* Wt;
  const void* bias = nullptr;
  float* out;
  switch (g) {
    case 0:  Wt = WtD; bias = We1b; out = P1; break;
    case 1:  Wt = WtE; out = Q1; break;
    case 2:  Wt = WtF; bias = Wu1b; out = P2; break;
    case 3:  Wt = WtG; out = Q2; break;
    default: Wt = WtH; bias = Wmb; out = msgv; break;
  }
  const bfloat* Ag = hb + (size_t)rb * 65536;
  const bfloat* Bg = Wt + (size_t)cbv * 65536;

  const int t = threadIdx.x, lane = t & 63, wave = t >> 6;
  const int wrow = wave >> 1, wcol = wave & 1;
  const int l15 = lane & 15, q = lane >> 4;

  const int row0 = t >> 2, p0 = t & 3, g0 = p0 ^ ((row0 >> 1) & 3);
  const int row1 = 64 + row0, g1 = p0 ^ ((row1 >> 1) & 3);
  const char* srcA0 = (const char*)(Ag + (size_t)row0 * 512 + g0 * 8);
  const char* srcA1 = (const char*)(Ag + (size_t)row1 * 512 + g1 * 8);
  const char* srcB0 = (const char*)(Bg + (size_t)row0 * 512 + g0 * 8);
  const char* srcB1 = (const char*)(Bg + (size_t)row1 * 512 + g1 * 8);
  const int dst0 = wave * 1024, dst1 = 4096 + wave * 1024;

  auto stage = [&](int kt2, int sel2) {
    const int koff = kt2 * 64;
    char* dA = smem + sel2 * 8192;
    char* dB = smem + 24576 + sel2 * 8192;
    g2l16(srcA0 + koff, dA + dst0);
    g2l16(srcA1 + koff, dA + dst1);
    g2l16(srcB0 + koff, dB + dst0);
    g2l16(srcB1 + koff, dB + dst1);
  };
  stage(0, 0);
  stage(1, 1);

  const int swz = (q ^ ((l15 >> 1) & 3)) * 16;
  const int fA = (wrow * 64 + l15) * 64 + swz;
  const int fB = (wcol * 64 + l15) * 64 + swz;

#pragma unroll
  for (int kt = 0; kt < 16; ++kt) {
    if (kt < 15) asm volatile("s_waitcnt vmcnt(4)" ::: "memory");
    else         asm volatile("s_waitcnt vmcnt(0)" ::: "memory");
    __builtin_amdgcn_s_barrier();
    if (kt < 14) stage(kt + 2, (kt + 2) % 3);
    const char* A = smem + (kt % 3) * 8192;
    const char* B = smem + 24576 + (kt % 3) * 8192;
    bf16x8 afr[4], bfr[4];
#pragma unroll
    for (int mi = 0; mi < 4; ++mi) afr[mi] = *(const bf16x8*)(A + fA + mi * 1024);
#pragma unroll
    for (int ni = 0; ni < 4; ++ni) bfr[ni] = *(const bf16x8*)(B + fB + ni * 1024);
#pragma unroll
    for (int mi = 0; mi < 4; ++mi)
#pragma unroll
      for (int ni = 0; ni < 4; ++ni)
        acc[mi][ni] =
            __builtin_amdgcn_mfma_f32_16x16x32_bf16(afr[mi], bfr[ni], acc[mi][ni], 0, 0, 0);
  }

  float bv[4];
#pragma unroll
  for (int ni = 0; ni < 4; ++ni)
    bv[ni] = bias ? ldf(bias, (size_t)cbv * 128 + wcol * 64 + ni * 16 + l15, fl) : 0.f;
#pragma unroll
  for (int mi = 0; mi < 4; ++mi)
#pragma unroll
    for (int rr = 0; rr < 4; ++rr) {
      const int j = wrow * 64 + mi * 16 + q * 4 + rr;
#pragma unroll
      for (int ni = 0; ni < 4; ++ni) {
        const int cc = wcol * 64 + ni * 16 + l15;
        out[(size_t)(rb * 128 + j) * 512 + cbv * 128 + cc] = acc[mi][ni][rr] + bv[ni];
      }
    }
}

// K3 (r2-proven): 128x128 tile, BK=32, 16 K-iters, 3-deep counted-vmcnt pipeline.
// LDS 52KB: A bufs [0,8K,16K), B bufs [24K,32K,40K), We2 tile [48K,52K).
// Epilogues reuse [0,32K) as the 128x128 bf16 swizzled image.
// uws != nullptr: u written linear (row m at uws + m*1024B).
__global__ __launch_bounds__(256) void k3_edge_mlp(const void* E, const bfloat* WtA,
                                                   const bfloat* WtB, const float* P1,
                                                   const float* Q1, const float* P2,
                                                   const float* Q2, const void* We2,
                                                   const int* flag, float* logits4,
                                                   bfloat* uws, void* dout) {
  const int f = *flag;
  __shared__ __align__(16) char smem[53248];
  f32x4 acc[4][4];
#pragma unroll
  for (int mi = 0; mi < 4; ++mi)
#pragma unroll
    for (int ni = 0; ni < 4; ++ni) acc[mi][ni] = (f32x4){0.f, 0.f, 0.f, 0.f};

  const int idx0 = blockIdx.x;                 // 0..4095
  const int bm = (idx0 >> 6) * 8 + (idx0 & 7); // XCD = bm&7
  const int bn = (idx0 >> 3) & 7;              // <4 attn, >=4 u
  const bool attn = bn < 4;
  const bfloat* Bg = attn ? WtA + (size_t)bn * 65536 : WtB + (size_t)(bn - 4) * 65536;
  const bfloat* Eb = (const bfloat*)E;
  const char* eb = (const char*)dout + 1048576;

  const int t = threadIdx.x;
  const int lane = t & 63;
  const int wave = t >> 6;
  const int wrow = wave >> 1, wcol = wave & 1;
  const int l15 = lane & 15;
  const int q = lane >> 4;
  const int blockcol = (attn ? bn : (bn - 4)) * 128;

  const int row0 = t >> 2, p0 = t & 3, g0 = p0 ^ ((row0 >> 1) & 3);
  const int row1 = 64 + row0, g1 = p0 ^ ((row1 >> 1) & 3);
  const char* srcB0 = (const char*)Bg + ((size_t)row0 * 512 + g0 * 8) * 2;
  const char* srcB1 = (const char*)Bg + ((size_t)row1 * 512 + g1 * 8) * 2;
  const char* srcA0;
  const char* srcA1;
  const int gr0 = bm * 128 + row0, gr1 = gr0 + 64;
  if (f) {
    srcA0 = eb + (size_t)(gr0 >> 6) * 131072 + (size_t)(gr0 & 63) * 1024 + (size_t)g0 * 16;
    srcA1 = eb + (size_t)(gr1 >> 6) * 131072 + (size_t)(gr1 & 63) * 1024 + (size_t)g1 * 16;
  } else {
    srcA0 = (const char*)Eb + ((size_t)gr0 * 512 + g0 * 8) * 2;
    srcA1 = (const char*)Eb + ((size_t)gr1 * 512 + g1 * 8) * 2;
  }
  const int dst0 = wave * 1024;           // + lane*16 added by HW
  const int dst1 = 4096 + wave * 1024;

  auto stage = [&](int kt2, int sel2) {
    char* dA = smem + sel2 * 8192;
    char* dB = smem + 24576 + sel2 * 8192;
    const int koff = kt2 * 64;
    g2l16(srcA0 + koff, dA + dst0);
    g2l16(srcA1 + koff, dA + dst1);
    g2l16(srcB0 + koff, dB + dst0);
    g2l16(srcB1 + koff, dB + dst1);
  };

  stage(0, 0);
  stage(1, 1);

  if (attn) {
    // fill sWe2 [16][128] bf16 at 48K: row n (h, zero-pad n>=8), swizzled like image
    for (int idx = t; idx < 2048; idx += 256) {
      const int n = idx >> 7, k = idx & 127;
      float v = (n < 8) ? ldf(We2, (size_t)(blockcol + k) * 8 + n, f) : 0.f;
      *(bfloat*)(smem + 49152 + (size_t)n * 256 + (((k >> 3) ^ n) * 16) + (k & 7) * 2) =
          __float2bfloat16(v);
    }
  }

  const int swzf = (q ^ ((l15 >> 1) & 3)) * 16;
  const int fA = (wrow * 64 + l15) * 64 + swzf;
  const int fB = (wcol * 64 + l15) * 64 + swzf;

#pragma unroll
  for (int kt = 0; kt < 16; ++kt) {
    if (kt < 15) asm volatile("s_waitcnt vmcnt(4)" ::: "memory");
    else         asm volatile("s_waitcnt vmcnt(0)" ::: "memory");
    __builtin_amdgcn_s_barrier();
    if (kt < 14) stage(kt + 2, (kt + 2) % 3);
    const char* A = smem + (kt % 3) * 8192;
    const char* B = smem + 24576 + (kt % 3) * 8192;
    bf16x8 afr[4], bfr[4];
#pragma unroll
    for (int mi = 0; mi < 4; ++mi) afr[mi] = *(const bf16x8*)(A + fA + mi * 1024);
#pragma unroll
    for (int ni = 0; ni < 4; ++ni) bfr[ni] = *(const bf16x8*)(B + fB + ni * 1024);
#pragma unroll
    for (int mi = 0; mi < 4; ++mi)
#pragma unroll
      for (int ni = 0; ni < 4; ++ni)
        acc[mi][ni] =
            __builtin_amdgcn_mfma_f32_16x16x32_bf16(afr[mi], bfr[ni], acc[mi][ni], 0, 0, 0);
  }

  const int b = bm >> 7;
  const float* P = attn ? P1 : P2;
  const float* Qm = attn ? Q1 : Q2;
  float pv[4];
#pragma unroll
  for (int ni = 0; ni < 4; ++ni)
    pv[ni] = P[(size_t)bm * 512 + blockcol + wcol * 64 + ni * 16 + l15];

  __syncthreads();  // last tile's frag reads retired before smem reuse as image

  if (!attn) {
    // write phase: val(j, cc) at j*256 + ((cc>>3)^(j&15))*16 + (cc&7)*2
#pragma unroll
    for (int mi = 0; mi < 4; ++mi)
#pragma unroll
      for (int rr = 0; rr < 4; ++rr) {
        const int j = wrow * 64 + mi * 16 + q * 4 + rr;
#pragma unroll
        for (int ni = 0; ni < 4; ++ni) {
          const int cc = wcol * 64 + ni * 16 + l15;
          const int c = blockcol + cc;
          float x = acc[mi][ni][rr] + pv[ni] + Qm[((size_t)b * 128 + j) * 512 + c];
          *(bfloat*)(smem + (size_t)j * 256 + (((cc >> 3) ^ (j & 15)) * 16) + (cc & 7) * 2) =
              __float2bfloat16(gelu_f(x));
        }
      }
    __syncthreads();
    char* ubase;
    size_t blkstride;
    if (uws) { ubase = (char*)uws; blkstride = 65536; }
    else if (f) { ubase = (char*)dout + 1048576 + 65536; blkstride = 131072; }
    else { ubase = (char*)dout + 524288; blkstride = 65536; }
#pragma unroll
    for (int rd = 0; rd < 8; ++rd) {
      const int j = rd * 16 + (t >> 4);
      const int ch = t & 15;
      f32x4 v = *(const f32x4*)(smem + (size_t)j * 256 + ((ch ^ (j & 15)) * 16));
      const size_t m = (size_t)bm * 128 + j;
      *(f32x4*)(ubase + (m >> 6) * blkstride + (m & 63) * 1024 + (size_t)blockcol * 2 +
                (size_t)ch * 16) = v;
    }
  } else {
#pragma unroll
    for (int mi = 0; mi < 4; ++mi)
#pragma unroll
      for (int rr = 0; rr < 4; ++rr) {
        const int j = wrow * 64 + mi * 16 + q * 4 + rr;
#pragma unroll
        for (int ni = 0; ni < 4; ++ni) {
          const int cc = wcol * 64 + ni * 16 + l15;
          const int c = blockcol + cc;
          float x = acc[mi][ni][rr] + pv[ni] + Qm[((size_t)b * 128 + j) * 512 + c];
          float e4 = (x >= 0.f) ? x : 0.2f * x;
          *(bfloat*)(smem + (size_t)j * 256 + (((cc >> 3) ^ (j & 15)) * 16) + (cc & 7) * 2) =
              __float2bfloat16(e4);
        }
      }
    __syncthreads();
    f32x4 acc2[2];
    acc2[0] = (f32x4){0.f, 0.f, 0.f, 0.f};
    acc2[1] = (f32x4){0.f, 0.f, 0.f, 0.f};
    const int jb = wave * 32;
#pragma unroll
    for (int ks = 0; ks < 4; ++ks) {
      const int gA = ((ks * 4 + q) ^ l15) * 16;
      bf16x8 a0 = *(const bf16x8*)(smem + (size_t)(jb + l15) * 256 + gA);
      bf16x8 a1 = *(const bf16x8*)(smem + (size_t)(jb + 16 + l15) * 256 + gA);
      bf16x8 bb = *(const bf16x8*)(smem + 49152 + (size_t)l15 * 256 + gA);
      acc2[0] = __builtin_amdgcn_mfma_f32_16x16x32_bf16(a0, bb, acc2[0], 0, 0, 0);
      acc2[1] = __builtin_amdgcn_mfma_f32_16x16x32_bf16(a1, bb, acc2[1], 0, 0, 0);
    }
#pragma unroll
    for (int mi2 = 0; mi2 < 2; ++mi2)
#pragma unroll
      for (int rr = 0; rr < 4; ++rr) {
        if (l15 < 8) {
          const int j = jb + mi2 * 16 + q * 4 + rr;
          logits4[(((size_t)bn * 512 + bm) * 128 + j) * 8 + l15] = acc2[mi2][rr];
        }
      }
  }
}

// K6 (ws path): out = E + u@Wu2 + b as a clean 128x128-tile GEMM. Grid 2048
// (512 rb x 4 cb, XCD = rb&7 matches k3's u writes). LDS 48KB -> 3 blocks/CU.
// Residual from original E; output written directly (no aliasing).
__global__ __launch_bounds__(256) void k6_ws(const bfloat* uws, const bfloat* WtC,
                                             const void* Wu2b, const void* E,
                                             const int* flag, void* dout) {
  const int f = *flag;
  __shared__ __align__(16) char smem[49152];
  f32x4 acc[4][4];
#pragma unroll
  for (int mi = 0; mi < 4; ++mi)
#pragma unroll
    for (int ni = 0; ni < 4; ++ni) acc[mi][ni] = (f32x4){0.f, 0.f, 0.f, 0.f};

  const int idx0 = blockIdx.x;                  // 0..2047
  const int rb = (idx0 >> 5) * 8 + (idx0 & 7);  // 0..511, XCD = rb&7
  const int cb = (idx0 >> 3) & 3;

  const int t = threadIdx.x, lane = t & 63, wave = t >> 6;
  const int wrow = wave >> 1, wcol = wave & 1;
  const int l15 = lane & 15, q = lane >> 4;

  const bfloat* Bg = WtC + (size_t)cb * 65536;
  const int row0 = t >> 2, p0 = t & 3, g0 = p0 ^ ((row0 >> 1) & 3);
  const int row1 = 64 + row0, g1 = p0 ^ ((row1 >> 1) & 3);
  const char* srcA0 = (const char*)uws + (size_t)(rb * 128 + row0) * 1024 + (size_t)g0 * 16;
  const char* srcA1 = (const char*)uws + (size_t)(rb * 128 + row1) * 1024 + (size_t)g1 * 16;
  const char* srcB0 = (const char*)(Bg + (size_t)row0 * 512 + g0 * 8);
  const char* srcB1 = (const char*)(Bg + (size_t)row1 * 512 + g1 * 8);
  const int dst0 = wave * 1024, dst1 = 4096 + wave * 1024;

  auto stage = [&](int kt2, int sel2) {
    const int koff = kt2 * 64;
    char* dA = smem + sel2 * 8192;
    char* dB = smem + 24576 + sel2 * 8192;
    g2l16(srcA0 + koff, dA + dst0);
    g2l16(srcA1 + koff, dA + dst1);
    g2l16(srcB0 + koff, dB + dst0);
    g2l16(srcB1 + koff, dB + dst1);
  };
  stage(0, 0);
  stage(1, 1);

  const int swz = (q ^ ((l15 >> 1) & 3)) * 16;
  const int fA = (wrow * 64 + l15) * 64 + swz;
  const int fB = (wcol * 64 + l15) * 64 + swz;

#pragma unroll
  for (int kt = 0; kt < 16; ++kt) {
    if (kt < 15) asm volatile("s_waitcnt vmcnt(4)" ::: "memory");
    else         asm volatile("s_waitcnt vmcnt(0)" ::: "memory");
    __builtin_amdgcn_s_barrier();
    if (kt < 14) stage(kt + 2, (kt + 2) % 3);
    const char* A = smem + (kt % 3) * 8192;
    const char* B = smem + 24576 + (kt % 3) * 8192;
    bf16x8 afr[4], bfr[4];
#pragma unroll
    for (int mi = 0; mi < 4; ++mi) afr[mi] = *(const bf16x8*)(A + fA + mi * 1024);
#pragma unroll
    for (int ni = 0; ni < 4; ++ni) bfr[ni] = *(const bf16x8*)(B + fB + ni * 1024);
#pragma unroll
    for (int mi = 0; mi < 4; ++mi)
#pragma unroll
      for (int ni = 0; ni < 4; ++ni)
        acc[mi][ni] =
            __builtin_amdgcn_mfma_f32_16x16x32_bf16(afr[mi], bfr[ni], acc[mi][ni], 0, 0, 0);
  }

  float wb[4];
#pragma unroll
  for (int ni = 0; ni < 4; ++ni)
    wb[ni] = ldf(Wu2b, (size_t)cb * 128 + wcol * 64 + ni * 16 + l15, f);
#pragma unroll
  for (int mi = 0; mi < 4; ++mi)
#pragma unroll
    for (int rr = 0; rr < 4; ++rr) {
      const int j = wrow * 64 + mi * 16 + q * 4 + rr;
      const size_t row = (size_t)rb * 128 + j;
#pragma unroll
      for (int ni = 0; ni < 4; ++ni) {
        const int c = cb * 128 + wcol * 64 + ni * 16 + l15;
        float r = f ? ((const float*)E)[row * 512 + c]
                    : __bfloat162float(((const bfloat*)E)[row * 512 + c]);
        stf(dout, 262144 + row * 512 + c, acc[mi][ni][rr] + wb[ni] + r, f);
      }
    }
}

// K6 fallback (small ws): r1 chunk-owning in-place version. 36KB LDS.
__global__ __launch_bounds__(512) void k6_chunk(const bfloat* WtC, const void* Wu2b,
                                                const void* E, const int* flag, void* dout) {
  const int f = *flag;
  __shared__ __align__(16) char smem[36864];
  char* sA = smem;          // 64 rows x 64B
  char* sB = smem + 4096;   // 512 rows x 64B
  f32x4 acc[2][8];
#pragma unroll
  for (int mi = 0; mi < 2; ++mi)
#pragma unroll
    for (int ni = 0; ni < 8; ++ni) acc[mi][ni] = (f32x4){0.f, 0.f, 0.f, 0.f};

  const int e = blockIdx.x & 7;
  const int x = blockIdx.x >> 3;
  const int bm = 2 * e + 16 * (x >> 1) + (x & 1);  // chunk 0..1023
  const int t = threadIdx.x;
  const int lane = t & 63;
  const int wave = t >> 6;
  const int wm = wave >> 2, wn = wave & 3;
  const int l15 = lane & 15;
  const int q = lane >> 4;
  const size_t r0 = (size_t)bm * 64;
  const char* ua = (const char*)dout +
                   (f ? (1048576 + (size_t)bm * 131072 + 65536) : (524288 + (size_t)bm * 65536));

  for (int kt = 0; kt < 16; ++kt) {
    __syncthreads();
    const int k0 = kt * 32;
    if (t < 256) {
      const int row = t >> 2;
      const int gseg = (t & 3) ^ ((row >> 1) & 3);
      g2l16(ua + (size_t)row * 1024 + (size_t)(k0 + gseg * 8) * 2, sA + wave * 64 * 16);
    }
#pragma unroll
    for (int c = 0; c < 4; ++c) {
      const int idx = c * 512 + t;
      const int row = idx >> 2;
      const int gseg = (idx & 3) ^ ((row >> 1) & 3);
      g2l16(WtC + (size_t)row * 512 + k0 + gseg * 8, sB + (c * 512 + wave * 64) * 16);
    }
    __syncthreads();
    bf16x8 afr[2], bfr[8];
#pragma unroll
    for (int mi = 0; mi < 2; ++mi) {
      const int r = wm * 32 + mi * 16 + l15;
      afr[mi] = *(const bf16x8*)(sA + ((size_t)r * 32 + (q ^ ((r >> 1) & 3)) * 8) * 2);
    }
#pragma unroll
    for (int ni = 0; ni < 8; ++ni) {
      const int r = wn * 128 + ni * 16 + l15;
      bfr[ni] = *(const bf16x8*)(sB + ((size_t)r * 32 + (q ^ ((r >> 1) & 3)) * 8) * 2);
    }
#pragma unroll
    for (int mi = 0; mi < 2; ++mi)
#pragma unroll
      for (int ni = 0; ni < 8; ++ni)
        acc[mi][ni] = __builtin_amdgcn_mfma_f32_16x16x32_bf16(afr[mi], bfr[ni], acc[mi][ni], 0, 0, 0);
  }
  float wb[8];
#pragma unroll
  for (int ni = 0; ni < 8; ++ni) wb[ni] = ldf(Wu2b, wn * 128 + ni * 16 + l15, f);
  const bfloat* eres = (const bfloat*)((const char*)dout + 1048576 + (size_t)bm * 131072);
#pragma unroll
  for (int mi = 0; mi < 2; ++mi)
#pragma unroll
    for (int rr = 0; rr < 4; ++rr) {
      const int j = wm * 32 + mi * 16 + q * 4 + rr;
#pragma unroll
      for (int ni = 0; ni < 8; ++ni) {
        const int c = wn * 128 + ni * 16 + l15;
        float r = f ? __bfloat162float(eres[(size_t)j * 512 + c])
                    : __bfloat162float(((const bfloat*)E)[(r0 + j) * 512 + c]);
        acc[mi][ni][rr] += wb[ni] + r;
      }
    }
  __syncthreads();
#pragma unroll
  for (int mi = 0; mi < 2; ++mi)
#pragma unroll
    for (int rr = 0; rr < 4; ++rr) {
      const int j = wm * 32 + mi * 16 + q * 4 + rr;
      const size_t row = r0 + j;
#pragma unroll
      for (int ni = 0; ni < 8; ++ni) {
        const int c = wn * 128 + ni * 16 + l15;
        stf(dout, 262144 + row * 512 + c, acc[mi][ni][rr], f);
      }
    }
}

// shfl_xor-based; 8 h's reduced simultaneously, 3 barriers total.
__global__ __launch_bounds__(128) void softmax_mean(const float* logits4, const void* adj,
                                                    const int* flag, float* amean) {
  const int f = *flag;
  const int bi = blockIdx.x;
  const int j = threadIdx.x;   // 0..127
  const int wv = j >> 6;
  __shared__ float sred[2][8];
  f32x4 v0 = (f32x4){0.f, 0.f, 0.f, 0.f}, v1 = (f32x4){0.f, 0.f, 0.f, 0.f};
#pragma unroll
  for (int s = 0; s < 4; ++s) {
    const float* p = logits4 + (((size_t)s * 512 + bi) * 128 + j) * 8;
    v0 += *(const f32x4*)p;
    v1 += *(const f32x4*)(p + 4);
  }
  float xv[8], m[8];
#pragma unroll
  for (int k = 0; k < 4; ++k) { xv[k] = v0[k]; xv[4 + k] = v1[k]; }
#pragma unroll
  for (int h = 0; h < 8; ++h) m[h] = xv[h];
#pragma unroll
  for (int o = 1; o < 64; o <<= 1)
#pragma unroll
    for (int h = 0; h < 8; ++h) m[h] = fmaxf(m[h], __shfl_xor(m[h], o));
  if ((j & 63) == 0) {
#pragma unroll
    for (int h = 0; h < 8; ++h) sred[wv][h] = m[h];
  }
  __syncthreads();
  float ex[8], s8[8];
#pragma unroll
  for (int h = 0; h < 8; ++h) {
    float mx = fmaxf(sred[0][h], sred[1][h]);
    ex[h] = __expf(xv[h] - mx);
    s8[h] = ex[h];
  }
#pragma unroll
  for (int o = 1; o < 64; o <<= 1)
#pragma unroll
    for (int h = 0; h < 8; ++h) s8[h] += __shfl_xor(s8[h], o);
  __syncthreads();
  if ((j & 63) == 0) {
#pragma unroll
    for (int h = 0; h < 8; ++h) sred[wv][h] = s8[h];
  }
  __syncthreads();
  float macc = 0.f;
#pragma unroll
  for (int h = 0; h < 8; ++h) macc += ex[h] / (sred[0][h] + sred[1][h]);
  amean[(size_t)bi * 128 + j] = macc * 0.125f * ldf(adj, (size_t)bi * 128 + j, f);
}

// fused aggregate + Wo + LayerNorm. 4 rows/block (128 blocks), shfl LN.
__global__ __launch_bounds__(256) void node_fused(const float* amean, const float* msg,
                                                  const void* Wo, const void* Wob,
                                                  const void* node, const void* lng,
                                                  const void* lnb, const int* flag, void* dout) {
  const int f = *flag;
  const int r0 = blockIdx.x * 4;     // rows r0..r0+3, same batch (128%4==0)
  const int b = r0 >> 7;
  const int t = threadIdx.x;
  const int lane = t & 63, wave = t >> 6;
  __shared__ float am[512];
  __shared__ float sAgg[4][512];
  __shared__ float sw[4][4];
  __shared__ float sw2[4][4];
  am[t] = amean[(size_t)r0 * 128 + t];
  am[t + 256] = amean[(size_t)r0 * 128 + t + 256];
  __syncthreads();
  float a0[4] = {0.f, 0.f, 0.f, 0.f}, a1[4] = {0.f, 0.f, 0.f, 0.f};
#pragma unroll 2
  for (int jj = 0; jj < 128; ++jj) {
    const float* mr = msg + ((size_t)b * 128 + jj) * 512;
    float m0 = mr[t], m1 = mr[t + 256];
#pragma unroll
    for (int r = 0; r < 4; ++r) {
      a0[r] += am[r * 128 + jj] * m0;
      a1[r] += am[r * 128 + jj] * m1;
    }
  }
#pragma unroll
  for (int r = 0; r < 4; ++r) { sAgg[r][t] = a0[r]; sAgg[r][t + 256] = a1[r]; }
  __syncthreads();
  float v0[4] = {0.f, 0.f, 0.f, 0.f}, v1[4] = {0.f, 0.f, 0.f, 0.f};
  if (f) {
    const float* W = (const float*)Wo;
#pragma unroll 2
    for (int k = 0; k < 512; ++k) {
      float w0 = W[(size_t)k * 512 + t], w1 = W[(size_t)k * 512 + t + 256];
#pragma unroll
      for (int r = 0; r < 4; ++r) { v0[r] += sAgg[r][k] * w0; v1[r] += sAgg[r][k] * w1; }
    }
  } else {
    const bfloat* W = (const bfloat*)Wo;
#pragma unroll 2
    for (int k = 0; k < 512; ++k) {
      float w0 = __bfloat162float(W[(size_t)k * 512 + t]);
      float w1 = __bfloat162float(W[(size_t)k * 512 + t + 256]);
#pragma unroll
      for (int r = 0; r < 4; ++r) { v0[r] += sAgg[r][k] * w0; v1[r] += sAgg[r][k] * w1; }
    }
  }
  float wob0 = ldf(Wob, t, f), wob1 = ldf(Wob, t + 256, f);
#pragma unroll
  for (int r = 0; r < 4; ++r) {
    v0[r] += wob0 + ldf(node, (size_t)(r0 + r) * 512 + t, f);
    v1[r] += wob1 + ldf(node, (size_t)(r0 + r) * 512 + t + 256, f);
  }
  float s[4];
#pragma unroll
  for (int r = 0; r < 4; ++r) s[r] = v0[r] + v1[r];
#pragma unroll
  for (int o = 1; o < 64; o <<= 1)
#pragma unroll
    for (int r = 0; r < 4; ++r) s[r] += __shfl_xor(s[r], o);
  if (lane == 0) {
#pragma unroll
    for (int r = 0; r < 4; ++r) sw[wave][r] = s[r];
  }
  __syncthreads();
  float mean[4];
#pragma unroll
  for (int r = 0; r < 4; ++r)
    mean[r] = (sw[0][r] + sw[1][r] + sw[2][r] + sw[3][r]) * (1.f / 512.f);
#pragma unroll
  for (int r = 0; r < 4; ++r) {
    float d0 = v0[r] - mean[r], d1 = v1[r] - mean[r];
    s[r] = d0 * d0 + d1 * d1;
  }
#pragma unroll
  for (int o = 1; o < 64; o <<= 1)
#pragma unroll
    for (int r = 0; r < 4; ++r) s[r] += __shfl_xor(s[r], o);
  if (lane == 0) {
#pragma unroll
    for (int r = 0; r < 4; ++r) sw2[wave][r] = s[r];
  }
  __syncthreads();
  float g0v = ldf(lng, t, f), g1v = ldf(lng, t + 256, f);
  float b0v = ldf(lnb, t, f), b1v = ldf(lnb, t + 256, f);
#pragma unroll
  for (int r = 0; r < 4; ++r) {
    float var = (sw2[0][r] + sw2[1][r] + sw2[2][r] + sw2[3][r]) * (1.f / 512.f);
    float inv = rsqrtf(var + 1e-5f);
    stf(dout, (size_t)(r0 + r) * 512 + t, (v0[r] - mean[r]) * inv * g0v + b0v, f);
    stf(dout, (size_t)(r0 + r) * 512 + t + 256, (v1[r] - mean[r]) * inv * g1v + b1v, f);
  }
}

extern "C" void kernel_launch(void* const* d_in, const int* in_sizes, int n_in, void* d_out,
                              int out_size, void* d_ws, size_t ws_size, hipStream_t stream) {
  (void)in_sizes; (void)n_in; (void)out_size;
  const void* node = d_in[0];
  const void* edge = d_in[1];
  const void* adj = d_in[2];
  const void* Wn_w = d_in[3];
  const void* Wn_b = d_in[4];
  const void* We1_w = d_in[5];
  const void* We1_b = d_in[6];
  const void* We2_w = d_in[7];
  // d_in[8] = We2_b: constant over j -> cancels in softmax, unused.
  const void* Wm_w = d_in[9];
  const void* Wm_b = d_in[10];
  const void* Wu1_w = d_in[11];
  const void* Wu1_b = d_in[12];
  const void* Wu2_w = d_in[13];
  const void* Wu2_b = d_in[14];
  const void* Wo_w = d_in[15];
  const void* Wo_b = d_in[16];
  const void* ln_g = d_in[17];
  const void* ln_b = d_in[18];

  char* w = (char*)d_ws;
  int* flag = (int*)w;        w += 256;
  float* h = (float*)w;       w += 262144 * 4;
  float* P1 = (float*)w;      w += 262144 * 4;
  float* Q1 = (float*)w;      w += 262144 * 4;
  float* P2 = (float*)w;      w += 262144 * 4;
  float* Q2 = (float*)w;      w += 262144 * 4;
  float* msg = (float*)w;     w += 262144 * 4;
  float* logits4 = (float*)w; w += (size_t)4 * 524288 * 4;  // [4][512][128][8] fp32 = 8MB
  float* amean = (float*)w;   w += 65536 * 4;
  bfloat* WtA = (bfloat*)w;   w += 262144 * 2;
  bfloat* WtB = (bfloat*)w;   w += 262144 * 2;
  bfloat* WtC = (bfloat*)w;   w += 262144 * 2;
  bfloat* WtD = (bfloat*)w;   w += 262144 * 2;
  bfloat* WtE = (bfloat*)w;   w += 262144 * 2;
  bfloat* WtF = (bfloat*)w;   w += 262144 * 2;
  bfloat* WtG = (bfloat*)w;   w += 262144 * 2;
  bfloat* WtH = (bfloat*)w;   w += 262144 * 2;
  bfloat* hb = (bfloat*)w;    w += 262144 * 2;
  bfloat* u_ws = (bfloat*)w;  w += (size_t)65536 * 1024;  // 64MB: u linear, 1024B rows
  const int uws_ok = (ws_size >= (size_t)(w - (char*)d_ws)) ? 1 : 0;
  if (!uws_ok) u_ws = nullptr;

  detect_dtype<<<1, 256, 0, stream>>>((const unsigned short*)node, flag);
  cvt_edge<<<16384, 256, 0, stream>>>((const float*)edge, flag, d_out);
  transpose8<<<512, 256, 0, stream>>>(We1_w, Wu1_w, Wu2_w, Wm_w, flag, WtA, WtB, WtC,
                                      WtD, WtE, WtF, WtG, WtH);
  small_gemm<<<128, 256, 0, stream>>>(node, 0, Wn_w, 0, Wn_b, flag, h, hb);
  fused5_mfma<<<80, 256, 0, stream>>>(hb, WtD, WtE, WtF, WtG, WtH, We1_b, Wu1_b, Wm_b, flag,
                                      P1, Q1, P2, Q2, msg);
  k3_edge_mlp<<<4096, 256, 0, stream>>>(edge, WtA, WtB, P1, Q1, P2, Q2, We2_w, flag,
                                        logits4, u_ws, d_out);
  softmax_mean<<<512, 128, 0, stream>>>(logits4, adj, flag, amean);
  node_fused<<<128, 256, 0, stream>>>(amean, msg, Wo_w, Wo_b, node, ln_g, ln_b, flag, d_out);
  if (uws_ok)
    k6_ws<<<2048, 256, 0, stream>>>(u_ws, WtC, Wu2_b, edge, flag, d_out);
  else
    k6_chunk<<<1024, 512, 0, stream>>>(WtC, Wu2_b, edge, flag, d_out);
}

// Round 5
// 715.767 us; speedup vs baseline: 1.1507x; 1.0305x over previous
//
#include <hip/hip_runtime.h>
#include <hip/hip_bf16.h>

// GraphConvLayer B=4,N=128,D=512,H=8. Input dtype (bf16|fp32) runtime-detected
// -> flag in ws; output dtype follows input dtype.
// f==1: E pre-converted to bf16 into d_out's outE region (chunk c: 64 rows at
//   [1048576 + c*131072, +131072): [Ebf16 64x1024B | u 64x1024B]).
// u placement: if ws_size permits, u -> u_ws (linear 1024B rows) for BOTH f
//   modes; k6_ws is a clean 128x128-tile GEMM (48KB LDS, 3 blocks/CU).
//   Fallback: r1 chunk k6.
// r5: (a) k6_ws staging FIXED to 4 loads/stage (r4 had 6 loads vs vmcnt(4) ->
//   full latency exposure every iter, 147us); (b) cvt_edge+transpose8+small_gemm
//   fused into one `prep` launch (9->7 launches; launch-overhead diagnostic).
// Occupancy lesson (r3): latency-bound family; 3 blocks/CU beats 2 with 2x
//   MFMA/iter. Keep LDS <= ~52KB.
// XCD-locality: cvt/k3/k6 grids swizzled so row-block rb is produced and
//   consumed on XCD rb&7.

typedef __bf16  bf16x8 __attribute__((ext_vector_type(8)));
typedef float   f32x4  __attribute__((ext_vector_type(4)));
typedef __hip_bfloat16 bfloat;

#define AS1 __attribute__((address_space(1)))
#define AS3 __attribute__((address_space(3)))

__device__ __forceinline__ void g2l16(const void* g, void* l) {
  __builtin_amdgcn_global_load_lds((AS1 void*)g, (AS3 void*)l, 16, 0, 0);
}

__device__ __forceinline__ float ldf(const void* p, size_t i, int f) {
  return f ? ((const float*)p)[i] : __bfloat162float(((const bfloat*)p)[i]);
}
__device__ __forceinline__ void stf(void* p, size_t i, float v, int f) {
  if (f) ((float*)p)[i] = v;
  else   ((bfloat*)p)[i] = __float2bfloat16(v);
}

// tanh-form GELU (max abs err ~3e-4 vs exact erf form; well under threshold)
__device__ __forceinline__ float gelu_f(float x) {
  float y = 0.7978845608028654f * (x + 0.044715f * x * x * x);
  float e = __expf(2.0f * y);
  float t = 1.0f - 2.0f / (e + 1.0f);
  return 0.5f * x * (1.0f + t);
}

__global__ __launch_bounds__(256) void detect_dtype(const unsigned short* nu, int* flag) {
  __shared__ int bad;
  if (threadIdx.x == 0) bad = 0;
  __syncthreads();
  int local = 0;
  for (int i = threadIdx.x; i < 4096; i += 256) {
    int ex = (nu[i] >> 7) & 0xFF;
    if (ex >= 0xC0) local = 1;
  }
  if (local) atomicOr(&bad, 1);
  __syncthreads();
  if (threadIdx.x == 0) *flag = bad;
}

// Fused prep: blocks [0,512) = transpose8, [512,640) = small_gemm (h), 
// [640, 17024) = cvt_edge. All depend only on flag.
__global__ __launch_bounds__(256) void prep(const float* E, const void* We1, const void* Wu1,
                                            const void* Wu2, const void* Wm, const void* node,
                                            const void* Wn, const void* Wnb, const int* flag,
                                            void* dout,
                                            bfloat* WtA, bfloat* WtB, bfloat* WtC,
                                            bfloat* WtD, bfloat* WtE, bfloat* WtF,
                                            bfloat* WtG, bfloat* WtH,
                                            float* h, bfloat* hb) {
  const int f = *flag;
  const int bid = blockIdx.x;
  const int t = threadIdx.x;
  __shared__ __align__(16) float sT[64][65];   // 16.6KB; aliased by small_gemm part

  if (bid < 512) {
    // ---- transpose8: 64x64 LDS tile, coalesced both sides ----
    const int m = bid >> 6;
    const int tile = bid & 63;
    const int k0 = (tile >> 3) * 64, n0 = (tile & 7) * 64;
    const void* src;
    size_t woff = 0;
    bfloat* dst;
    switch (m) {
      case 0:  src = We1; woff = 524288; dst = WtA; break;
      case 1:  src = Wu1; woff = 524288; dst = WtB; break;
      case 2:  src = Wu2; dst = WtC; break;
      case 3:  src = We1; dst = WtD; break;
      case 4:  src = We1; woff = 262144; dst = WtE; break;
      case 5:  src = Wu1; dst = WtF; break;
      case 6:  src = Wu1; woff = 262144; dst = WtG; break;
      default: src = Wm; dst = WtH; break;
    }
#pragma unroll
    for (int p = 0; p < 4; ++p) {
      const int r = p * 16 + (t >> 4);
      const int cs = (t & 15) * 4;
      const size_t base = woff + (size_t)(k0 + r) * 512 + n0 + cs;
#pragma unroll
      for (int i = 0; i < 4; ++i) sT[r][cs + i] = ldf(src, base + i, f);
    }
    __syncthreads();
#pragma unroll
    for (int p = 0; p < 2; ++p) {
      const int n = p * 32 + (t >> 3);
      const int ks = (t & 7) * 8;
      bf16x8 v;
#pragma unroll
      for (int i = 0; i < 8; ++i) v[i] = (__bf16)sT[ks + i][n];
      *(bf16x8*)(dst + (size_t)(n0 + n) * 512 + k0 + ks) = v;
    }
  } else if (bid < 640) {
    // ---- small_gemm: h = node@Wn + b (fp32 + bf16 out) ----
    float (*sA)[512] = (float(*)[512])sT;
    const int r0 = (bid - 512) * 4;
    for (int idx = t; idx < 2048; idx += 256)
      sA[idx >> 9][idx & 511] = ldf(node, (size_t)(r0 + (idx >> 9)) * 512 + (idx & 511), f);
    __syncthreads();
    float acc0[4] = {0.f, 0.f, 0.f, 0.f}, acc1[4] = {0.f, 0.f, 0.f, 0.f};
#pragma unroll 4
    for (int k = 0; k < 512; ++k) {
      float w0 = ldf(Wn, (size_t)k * 512 + t, f);
      float w1 = ldf(Wn, (size_t)k * 512 + t + 256, f);
#pragma unroll
      for (int r = 0; r < 4; ++r) {
        acc0[r] += sA[r][k] * w0;
        acc1[r] += sA[r][k] * w1;
      }
    }
    float b0 = ldf(Wnb, t, f), b1 = ldf(Wnb, t + 256, f);
#pragma unroll
    for (int r = 0; r < 4; ++r) {
      float o0 = acc0[r] + b0, o1 = acc1[r] + b1;
      h[(size_t)(r0 + r) * 512 + t] = o0;
      h[(size_t)(r0 + r) * 512 + t + 256] = o1;
      hb[(size_t)(r0 + r) * 512 + t] = __float2bfloat16(o0);
      hb[(size_t)(r0 + r) * 512 + t + 256] = __float2bfloat16(o1);
    }
  } else {
    // ---- cvt_edge (f==1 only): E fp32 -> bf16 chunk layout in dout ----
    if (f == 0) return;
    const int idx = bid - 640;              // 0..16383, idx%8 preserved (640%8==0)
    const int e = idx & 7;
    const int x = idx >> 3;
    const int m = x >> 5;
    const int hh = (x >> 4) & 1;
    const int s = x & 15;
    const int c = 2 * e + 16 * m + hh;
    const int rloc = s * 4 + (t >> 6);
    const int c8 = t & 63;
    const float* src = E + ((size_t)c * 64 + rloc) * 512 + (size_t)c8 * 8;
    f32x4 lo = *(const f32x4*)src;
    f32x4 hi = *(const f32x4*)(src + 4);
    bf16x8 v;
    v[0] = (__bf16)lo[0]; v[1] = (__bf16)lo[1]; v[2] = (__bf16)lo[2]; v[3] = (__bf16)lo[3];
    v[4] = (__bf16)hi[0]; v[5] = (__bf16)hi[1]; v[6] = (__bf16)hi[2]; v[7] = (__bf16)hi[3];
    char* eb = (char*)dout + 1048576;
    *(bf16x8*)(eb + (size_t)c * 131072 + (size_t)rloc * 1024 + (size_t)c8 * 16) = v;
  }
}

// 5 h-GEMMs via MFMA. grid = g(5) x rb(4) x cb(4) = 80 blocks, 128x128 tiles.
__global__ __launch_bounds__(256) void fused5_mfma(const bfloat* hb, const bfloat* WtD,
                                                   const bfloat* WtE, const bfloat* WtF,
                                                   const bfloat* WtG, const bfloat* WtH,
                                                   const void* We1b, const void* Wu1b,
                                                   const void* Wmb, const int* flag,
                                                   float* P1, float* Q1, float* P2, float* Q2,
                                                   float* msgv) {
  const int fl = *flag;
  __shared__ __align__(16) char smem[49152];  // A 3x8K [0,24K) | B 3x8K [24K,48K)
  f32x4 acc[4][4];
#pragma unroll
  for (int mi = 0; mi < 4; ++mi)
#pragma unroll
    for (int ni = 0; ni < 4; ++ni) acc[mi][ni] = (f32x4){0.f, 0.f, 0.f, 0.f};

  const int bid = blockIdx.x;
  const int g = bid >> 4, rb = (bid >> 2) & 3, cbv = bid & 3;
  const bfloat* Wt;
  const void* bias = nullptr;
  float* out;
  switch (g) {
    case 0:  Wt = WtD; bias = We1b; out = P1; break;
    case 1:  Wt = WtE; out = Q1; break;
    case 2:  Wt = WtF; bias = Wu1b; out = P2; break;
    case 3:  Wt = WtG; out = Q2; break;
    default: Wt = WtH; bias = Wmb; out = msgv; break;
  }
  const bfloat* Ag = hb + (size_t)rb * 65536;
  const bfloat* Bg = Wt + (size_t)cbv * 65536;

  const int t = threadIdx.x, lane = t & 63, wave = t >> 6;
  const int wrow = wave >> 1, wcol = wave & 1;
  const int l15 = lane & 15, q = lane >> 4;

  const int row0 = t >> 2, p0 = t & 3, g0 = p0 ^ ((row0 >> 1) & 3);
  const int row1 = 64 + row0, g1 = p0 ^ ((row1 >> 1) & 3);
  const char* srcA0 = (const char*)(Ag + (size_t)row0 * 512 + g0 * 8);
  const char* srcA1 = (const char*)(Ag + (size_t)row1 * 512 + g1 * 8);
  const char* srcB0 = (const char*)(Bg + (size_t)row0 * 512 + g0 * 8);
  const char* srcB1 = (const char*)(Bg + (size_t)row1 * 512 + g1 * 8);
  const int dst0 = wave * 1024, dst1 = 4096 + wave * 1024;

  auto stage = [&](int kt2, int sel2) {
    const int koff = kt2 * 64;
    char* dA = smem + sel2 * 8192;
    char* dB = smem + 24576 + sel2 * 8192;
    g2l16(srcA0 + koff, dA + dst0);
    g2l16(srcA1 + koff, dA + dst1);
    g2l16(srcB0 + koff, dB + dst0);
    g2l16(srcB1 + koff, dB + dst1);
  };
  stage(0, 0);
  stage(1, 1);

  const int swz = (q ^ ((l15 >> 1) & 3)) * 16;
  const int fA = (wrow * 64 + l15) * 64 + swz;
  const int fB = (wcol * 64 + l15) * 64 + swz;

#pragma unroll
  for (int kt = 0; kt < 16; ++kt) {
    if (kt < 15) asm volatile("s_waitcnt vmcnt(4)" ::: "memory");
    else         asm volatile("s_waitcnt vmcnt(0)" ::: "memory");
    __builtin_amdgcn_s_barrier();
    if (kt < 14) stage(kt + 2, (kt + 2) % 3);
    const char* A = smem + (kt % 3) * 8192;
    const char* B = smem + 24576 + (kt % 3) * 8192;
    bf16x8 afr[4], bfr[4];
#pragma unroll
    for (int mi = 0; mi < 4; ++mi) afr[mi] = *(const bf16x8*)(A + fA + mi * 1024);
#pragma unroll
    for (int ni = 0; ni < 4; ++ni) bfr[ni] = *(const bf16x8*)(B + fB + ni * 1024);
#pragma unroll
    for (int mi = 0; mi < 4; ++mi)
#pragma unroll
      for (int ni = 0; ni < 4; ++ni)
        acc[mi][ni] =
            __builtin_amdgcn_mfma_f32_16x16x32_bf16(afr[mi], bfr[ni], acc[mi][ni], 0, 0, 0);
  }

  float bv[4];
#pragma unroll
  for (int ni = 0; ni < 4; ++ni)
    bv[ni] = bias ? ldf(bias, (size_t)cbv * 128 + wcol * 64 + ni * 16 + l15, fl) : 0.f;
#pragma unroll
  for (int mi = 0; mi < 4; ++mi)
#pragma unroll
    for (int rr = 0; rr < 4; ++rr) {
      const int j = wrow * 64 + mi * 16 + q * 4 + rr;
#pragma unroll
      for (int ni = 0; ni < 4; ++ni) {
        const int cc = wcol * 64 + ni * 16 + l15;
        out[(size_t)(rb * 128 + j) * 512 + cbv * 128 + cc] = acc[mi][ni][rr] + bv[ni];
      }
    }
}

// K3 (r2-proven): 128x128 tile, BK=32, 16 K-iters, 3-deep counted-vmcnt pipeline.
// LDS 52KB: A bufs [0,8K,16K), B bufs [24K,32K,40K), We2 tile [48K,52K).
// Epilogues reuse [0,32K) as the 128x128 bf16 swizzled image.
__global__ __launch_bounds__(256) void k3_edge_mlp(const void* E, const bfloat* WtA,
                                                   const bfloat* WtB, const float* P1,
                                                   const float* Q1, const float* P2,
                                                   const float* Q2, const void* We2,
                                                   const int* flag, float* logits4,
                                                   bfloat* uws, void* dout) {
  const int f = *flag;
  __shared__ __align__(16) char smem[53248];
  f32x4 acc[4][4];
#pragma unroll
  for (int mi = 0; mi < 4; ++mi)
#pragma unroll
    for (int ni = 0; ni < 4; ++ni) acc[mi][ni] = (f32x4){0.f, 0.f, 0.f, 0.f};

  const int idx0 = blockIdx.x;                 // 0..4095
  const int bm = (idx0 >> 6) * 8 + (idx0 & 7); // XCD = bm&7
  const int bn = (idx0 >> 3) & 7;              // <4 attn, >=4 u
  const bool attn = bn < 4;
  const bfloat* Bg = attn ? WtA + (size_t)bn * 65536 : WtB + (size_t)(bn - 4) * 65536;
  const bfloat* Eb = (const bfloat*)E;
  const char* eb = (const char*)dout + 1048576;

  const int t = threadIdx.x;
  const int lane = t & 63;
  const int wave = t >> 6;
  const int wrow = wave >> 1, wcol = wave & 1;
  const int l15 = lane & 15;
  const int q = lane >> 4;
  const int blockcol = (attn ? bn : (bn - 4)) * 128;

  const int row0 = t >> 2, p0 = t & 3, g0 = p0 ^ ((row0 >> 1) & 3);
  const int row1 = 64 + row0, g1 = p0 ^ ((row1 >> 1) & 3);
  const char* srcB0 = (const char*)Bg + ((size_t)row0 * 512 + g0 * 8) * 2;
  const char* srcB1 = (const char*)Bg + ((size_t)row1 * 512 + g1 * 8) * 2;
  const char* srcA0;
  const char* srcA1;
  const int gr0 = bm * 128 + row0, gr1 = gr0 + 64;
  if (f) {
    srcA0 = eb + (size_t)(gr0 >> 6) * 131072 + (size_t)(gr0 & 63) * 1024 + (size_t)g0 * 16;
    srcA1 = eb + (size_t)(gr1 >> 6) * 131072 + (size_t)(gr1 & 63) * 1024 + (size_t)g1 * 16;
  } else {
    srcA0 = (const char*)Eb + ((size_t)gr0 * 512 + g0 * 8) * 2;
    srcA1 = (const char*)Eb + ((size_t)gr1 * 512 + g1 * 8) * 2;
  }
  const int dst0 = wave * 1024;           // + lane*16 added by HW
  const int dst1 = 4096 + wave * 1024;

  auto stage = [&](int kt2, int sel2) {
    char* dA = smem + sel2 * 8192;
    char* dB = smem + 24576 + sel2 * 8192;
    const int koff = kt2 * 64;
    g2l16(srcA0 + koff, dA + dst0);
    g2l16(srcA1 + koff, dA + dst1);
    g2l16(srcB0 + koff, dB + dst0);
    g2l16(srcB1 + koff, dB + dst1);
  };

  stage(0, 0);
  stage(1, 1);

  if (attn) {
    // fill sWe2 [16][128] bf16 at 48K: row n (h, zero-pad n>=8), swizzled like image
    for (int idx = t; idx < 2048; idx += 256) {
      const int n = idx >> 7, k = idx & 127;
      float v = (n < 8) ? ldf(We2, (size_t)(blockcol + k) * 8 + n, f) : 0.f;
      *(bfloat*)(smem + 49152 + (size_t)n * 256 + (((k >> 3) ^ n) * 16) + (k & 7) * 2) =
          __float2bfloat16(v);
    }
  }

  const int swzf = (q ^ ((l15 >> 1) & 3)) * 16;
  const int fA = (wrow * 64 + l15) * 64 + swzf;
  const int fB = (wcol * 64 + l15) * 64 + swzf;

#pragma unroll
  for (int kt = 0; kt < 16; ++kt) {
    if (kt < 15) asm volatile("s_waitcnt vmcnt(4)" ::: "memory");
    else         asm volatile("s_waitcnt vmcnt(0)" ::: "memory");
    __builtin_amdgcn_s_barrier();
    if (kt < 14) stage(kt + 2, (kt + 2) % 3);
    const char* A = smem + (kt % 3) * 8192;
    const char* B = smem + 24576 + (kt % 3) * 8192;
    bf16x8 afr[4], bfr[4];
#pragma unroll
    for (int mi = 0; mi < 4; ++mi) afr[mi] = *(const bf16x8*)(A + fA + mi * 1024);
#pragma unroll
    for (int ni = 0; ni < 4; ++ni) bfr[ni] = *(const bf16x8*)(B + fB + ni * 1024);
#pragma unroll
    for (int mi = 0; mi < 4; ++mi)
#pragma unroll
      for (int ni = 0; ni < 4; ++ni)
        acc[mi][ni] =
            __builtin_amdgcn_mfma_f32_16x16x32_bf16(afr[mi], bfr[ni], acc[mi][ni], 0, 0, 0);
  }

  const int b = bm >> 7;
  const float* P = attn ? P1 : P2;
  const float* Qm = attn ? Q1 : Q2;
  float pv[4];
#pragma unroll
  for (int ni = 0; ni < 4; ++ni)
    pv[ni] = P[(size_t)bm * 512 + blockcol + wcol * 64 + ni * 16 + l15];

  __syncthreads();  // last tile's frag reads retired before smem reuse as image

  if (!attn) {
    // write phase: val(j, cc) at j*256 + ((cc>>3)^(j&15))*16 + (cc&7)*2
#pragma unroll
    for (int mi = 0; mi < 4; ++mi)
#pragma unroll
      for (int rr = 0; rr < 4; ++rr) {
        const int j = wrow * 64 + mi * 16 + q * 4 + rr;
#pragma unroll
        for (int ni = 0; ni < 4; ++ni) {
          const int cc = wcol * 64 + ni * 16 + l15;
          const int c = blockcol + cc;
          float x = acc[mi][ni][rr] + pv[ni] + Qm[((size_t)b * 128 + j) * 512 + c];
          *(bfloat*)(smem + (size_t)j * 256 + (((cc >> 3) ^ (j & 15)) * 16) + (cc & 7) * 2) =
              __float2bfloat16(gelu_f(x));
        }
      }
    __syncthreads();
    char* ubase;
    size_t blkstride;
    if (uws) { ubase = (char*)uws; blkstride = 65536; }
    else if (f) { ubase = (char*)dout + 1048576 + 65536; blkstride = 131072; }
    else { ubase = (char*)dout + 524288; blkstride = 65536; }
#pragma unroll
    for (int rd = 0; rd < 8; ++rd) {
      const int j = rd * 16 + (t >> 4);
      const int ch = t & 15;
      f32x4 v = *(const f32x4*)(smem + (size_t)j * 256 + ((ch ^ (j & 15)) * 16));
      const size_t m = (size_t)bm * 128 + j;
      *(f32x4*)(ubase + (m >> 6) * blkstride + (m & 63) * 1024 + (size_t)blockcol * 2 +
                (size_t)ch * 16) = v;
    }
  } else {
#pragma unroll
    for (int mi = 0; mi < 4; ++mi)
#pragma unroll
      for (int rr = 0; rr < 4; ++rr) {
        const int j = wrow * 64 + mi * 16 + q * 4 + rr;
#pragma unroll
        for (int ni = 0; ni < 4; ++ni) {
          const int cc = wcol * 64 + ni * 16 + l15;
          const int c = blockcol + cc;
          float x = acc[mi][ni][rr] + pv[ni] + Qm[((size_t)b * 128 + j) * 512 + c];
          float e4 = (x >= 0.f) ? x : 0.2f * x;
          *(bfloat*)(smem + (size_t)j * 256 + (((cc >> 3) ^ (j & 15)) * 16) + (cc & 7) * 2) =
              __float2bfloat16(e4);
        }
      }
    __syncthreads();
    f32x4 acc2[2];
    acc2[0] = (f32x4){0.f, 0.f, 0.f, 0.f};
    acc2[1] = (f32x4){0.f, 0.f, 0.f, 0.f};
    const int jb = wave * 32;
#pragma unroll
    for (int ks = 0; ks < 4; ++ks) {
      const int gA = ((ks * 4 + q) ^ l15) * 16;
      bf16x8 a0 = *(const bf16x8*)(smem + (size_t)(jb + l15) * 256 + gA);
      bf16x8 a1 = *(const bf16x8*)(smem + (size_t)(jb + 16 + l15) * 256 + gA);
      bf16x8 bb = *(const bf16x8*)(smem + 49152 + (size_t)l15 * 256 + gA);
      acc2[0] = __builtin_amdgcn_mfma_f32_16x16x32_bf16(a0, bb, acc2[0], 0, 0, 0);
      acc2[1] = __builtin_amdgcn_mfma_f32_16x16x32_bf16(a1, bb, acc2[1], 0, 0, 0);
    }
#pragma unroll
    for (int mi2 = 0; mi2 < 2; ++mi2)
#pragma unroll
      for (int rr = 0; rr < 4; ++rr) {
        if (l15 < 8) {
          const int j = jb + mi2 * 16 + q * 4 + rr;
          logits4[(((size_t)bn * 512 + bm) * 128 + j) * 8 + l15] = acc2[mi2][rr];
        }
      }
  }
}

// K6 (ws path, r5 FIXED staging): out = E + u@Wu2 + b as 128x128-tile GEMM.
// Grid 2048 (512 rb x 4 cb, XCD = rb&7 matches k3's u writes). LDS 48KB.
// Staging: 2 A + 2 B loads per stage (rows t>>2 and 64+t>>2), vmcnt(4).
__global__ __launch_bounds__(256) void k6_ws(const bfloat* uws, const bfloat* WtC,
                                             const void* Wu2b, const void* E,
                                             const int* flag, void* dout) {
  const int f = *flag;
  __shared__ __align__(16) char smem[49152];
  f32x4 acc[4][4];
#pragma unroll
  for (int mi = 0; mi < 4; ++mi)
#pragma unroll
    for (int ni = 0; ni < 4; ++ni) acc[mi][ni] = (f32x4){0.f, 0.f, 0.f, 0.f};

  const int idx0 = blockIdx.x;                  // 0..2047
  const int rb = (idx0 >> 5) * 8 + (idx0 & 7);  // 0..511, XCD = rb&7
  const int cb = (idx0 >> 3) & 3;

  const int t = threadIdx.x, lane = t & 63, wave = t >> 6;
  const int wrow = wave >> 1, wcol = wave & 1;
  const int l15 = lane & 15, q = lane >> 4;

  const bfloat* Bg = WtC + (size_t)cb * 65536;
  const int row0 = t >> 2, p0 = t & 3, g0 = p0 ^ ((row0 >> 1) & 3);
  const int row1 = 64 + row0, g1 = p0 ^ ((row1 >> 1) & 3);
  const char* srcA0 = (const char*)uws + (size_t)(rb * 128 + row0) * 1024 + (size_t)g0 * 16;
  const char* srcA1 = (const char*)uws + (size_t)(rb * 128 + row1) * 1024 + (size_t)g1 * 16;
  const char* srcB0 = (const char*)(Bg + (size_t)row0 * 512 + g0 * 8);
  const char* srcB1 = (const char*)(Bg + (size_t)row1 * 512 + g1 * 8);
  const int dst0 = wave * 1024, dst1 = 4096 + wave * 1024;

  auto stage = [&](int kt2, int sel2) {
    const int koff = kt2 * 64;
    char* dA = smem + sel2 * 8192;
    char* dB = smem + 24576 + sel2 * 8192;
    g2l16(srcA0 + koff, dA + dst0);
    g2l16(srcA1 + koff, dA + dst1);
    g2l16(srcB0 + koff, dB + dst0);
    g2l16(srcB1 + koff, dB + dst1);
  };
  stage(0, 0);
  stage(1, 1);

  const int swz = (q ^ ((l15 >> 1) & 3)) * 16;
  const int fA = (wrow * 64 + l15) * 64 + swz;
  const int fB = (wcol * 64 + l15) * 64 + swz;

#pragma unroll
  for (int kt = 0; kt < 16; ++kt) {
    if (kt < 15) asm volatile("s_waitcnt vmcnt(4)" ::: "memory");
    else         asm volatile("s_waitcnt vmcnt(0)" ::: "memory");
    __builtin_amdgcn_s_barrier();
    if (kt < 14) stage(kt + 2, (kt + 2) % 3);
    const char* A = smem + (kt % 3) * 8192;
    const char* B = smem + 24576 + (kt % 3) * 8192;
    bf16x8 afr[4], bfr[4];
#pragma unroll
    for (int mi = 0; mi < 4; ++mi) afr[mi] = *(const bf16x8*)(A + fA + mi * 1024);
#pragma unroll
    for (int ni = 0; ni < 4; ++ni) bfr[ni] = *(const bf16x8*)(B + fB + ni * 1024);
#pragma unroll
    for (int mi = 0; mi < 4; ++mi)
#pragma unroll
      for (int ni = 0; ni < 4; ++ni)
        acc[mi][ni] =
            __builtin_amdgcn_mfma_f32_16x16x32_bf16(afr[mi], bfr[ni], acc[mi][ni], 0, 0, 0);
  }

  float wb[4];
#pragma unroll
  for (int ni = 0; ni < 4; ++ni)
    wb[ni] = ldf(Wu2b, (size_t)cb * 128 + wcol * 64 + ni * 16 + l15, f);
#pragma unroll
  for (int mi = 0; mi < 4; ++mi)
#pragma unroll
    for (int rr = 0; rr < 4; ++rr) {
      const int j = wrow * 64 + mi * 16 + q * 4 + rr;
      const size_t row = (size_t)rb * 128 + j;
#pragma unroll
      for (int ni = 0; ni < 4; ++ni) {
        const int c = cb * 128 + wcol * 64 + ni * 16 + l15;
        float r = f ? ((const float*)E)[row * 512 + c]
                    : __bfloat162float(((const bfloat*)E)[row * 512 + c]);
        stf(dout, 262144 + row * 512 + c, acc[mi][ni][rr] + wb[ni] + r, f);
      }
    }
}

// K6 fallback (small ws): r1 chunk-owning in-place version. 36KB LDS.
__global__ __launch_bounds__(512) void k6_chunk(const bfloat* WtC, const void* Wu2b,
                                                const void* E, const int* flag, void* dout) {
  const int f = *flag;
  __shared__ __align__(16) char smem[36864];
  char* sA = smem;          // 64 rows x 64B
  char* sB = smem + 4096;   // 512 rows x 64B
  f32x4 acc[2][8];
#pragma unroll
  for (int mi = 0; mi < 2; ++mi)
#pragma unroll
    for (int ni = 0; ni < 8; ++ni) acc[mi][ni] = (f32x4){0.f, 0.f, 0.f, 0.f};

  const int e = blockIdx.x & 7;
  const int x = blockIdx.x >> 3;
  const int bm = 2 * e + 16 * (x >> 1) + (x & 1);
  const int t = threadIdx.x;
  const int lane = t & 63;
  const int wave = t >> 6;
  const int wm = wave >> 2, wn = wave & 3;
  const int l15 = lane & 15;
  const int q = lane >> 4;
  const size_t r0 = (size_t)bm * 64;
  const char* ua = (const char*)dout +
                   (f ? (1048576 + (size_t)bm * 131072 + 65536) : (524288 + (size_t)bm * 65536));

  for (int kt = 0; kt < 16; ++kt) {
    __syncthreads();
    const int k0 = kt * 32;
    if (t < 256) {
      const int row = t >> 2;
      const int gseg = (t & 3) ^ ((row >> 1) & 3);
      g2l16(ua + (size_t)row * 1024 + (size_t)(k0 + gseg * 8) * 2, sA + wave * 64 * 16);
    }
#pragma unroll
    for (int c = 0; c < 4; ++c) {
      const int idx = c * 512 + t;
      const int row = idx >> 2;
      const int gseg = (idx & 3) ^ ((row >> 1) & 3);
      g2l16(WtC + (size_t)row * 512 + k0 + gseg * 8, sB + (c * 512 + wave * 64) * 16);
    }
    __syncthreads();
    bf16x8 afr[2], bfr[8];
#pragma unroll
    for (int mi = 0; mi < 2; ++mi) {
      const int r = wm * 32 + mi * 16 + l15;
      afr[mi] = *(const bf16x8*)(sA + ((size_t)r * 32 + (q ^ ((r >> 1) & 3)) * 8) * 2);
    }
#pragma unroll
    for (int ni = 0; ni < 8; ++ni) {
      const int r = wn * 128 + ni * 16 + l15;
      bfr[ni] = *(const bf16x8*)(sB + ((size_t)r * 32 + (q ^ ((r >> 1) & 3)) * 8) * 2);
    }
#pragma unroll
    for (int mi = 0; mi < 2; ++mi)
#pragma unroll
      for (int ni = 0; ni < 8; ++ni)
        acc[mi][ni] = __builtin_amdgcn_mfma_f32_16x16x32_bf16(afr[mi], bfr[ni], acc[mi][ni], 0, 0, 0);
  }
  float wb[8];
#pragma unroll
  for (int ni = 0; ni < 8; ++ni) wb[ni] = ldf(Wu2b, wn * 128 + ni * 16 + l15, f);
  const bfloat* eres = (const bfloat*)((const char*)dout + 1048576 + (size_t)bm * 131072);
#pragma unroll
  for (int mi = 0; mi < 2; ++mi)
#pragma unroll
    for (int rr = 0; rr < 4; ++rr) {
      const int j = wm * 32 + mi * 16 + q * 4 + rr;
#pragma unroll
      for (int ni = 0; ni < 8; ++ni) {
        const int c = wn * 128 + ni * 16 + l15;
        float r = f ? __bfloat162float(eres[(size_t)j * 512 + c])
                    : __bfloat162float(((const bfloat*)E)[(r0 + j) * 512 + c]);
        acc[mi][ni][rr] += wb[ni] + r;
      }
    }
  __syncthreads();
#pragma unroll
  for (int mi = 0; mi < 2; ++mi)
#pragma unroll
    for (int rr = 0; rr < 4; ++rr) {
      const int j = wm * 32 + mi * 16 + q * 4 + rr;
      const size_t row = r0 + j;
#pragma unroll
      for (int ni = 0; ni < 8; ++ni) {
        const int c = wn * 128 + ni * 16 + l15;
        stf(dout, 262144 + row * 512 + c, acc[mi][ni][rr], f);
      }
    }
}

// shfl_xor-based; 8 h's reduced simultaneously, 3 barriers total.
__global__ __launch_bounds__(128) void softmax_mean(const float* logits4, const void* adj,
                                                    const int* flag, float* amean) {
  const int f = *flag;
  const int bi = blockIdx.x;
  const int j = threadIdx.x;   // 0..127
  const int wv = j >> 6;
  __shared__ float sred[2][8];
  f32x4 v0 = (f32x4){0.f, 0.f, 0.f, 0.f}, v1 = (f32x4){0.f, 0.f, 0.f, 0.f};
#pragma unroll
  for (int s = 0; s < 4; ++s) {
    const float* p = logits4 + (((size_t)s * 512 + bi) * 128 + j) * 8;
    v0 += *(const f32x4*)p;
    v1 += *(const f32x4*)(p + 4);
  }
  float xv[8], m[8];
#pragma unroll
  for (int k = 0; k < 4; ++k) { xv[k] = v0[k]; xv[4 + k] = v1[k]; }
#pragma unroll
  for (int h = 0; h < 8; ++h) m[h] = xv[h];
#pragma unroll
  for (int o = 1; o < 64; o <<= 1)
#pragma unroll
    for (int h = 0; h < 8; ++h) m[h] = fmaxf(m[h], __shfl_xor(m[h], o));
  if ((j & 63) == 0) {
#pragma unroll
    for (int h = 0; h < 8; ++h) sred[wv][h] = m[h];
  }
  __syncthreads();
  float ex[8], s8[8];
#pragma unroll
  for (int h = 0; h < 8; ++h) {
    float mx = fmaxf(sred[0][h], sred[1][h]);
    ex[h] = __expf(xv[h] - mx);
    s8[h] = ex[h];
  }
#pragma unroll
  for (int o = 1; o < 64; o <<= 1)
#pragma unroll
    for (int h = 0; h < 8; ++h) s8[h] += __shfl_xor(s8[h], o);
  __syncthreads();
  if ((j & 63) == 0) {
#pragma unroll
    for (int h = 0; h < 8; ++h) sred[wv][h] = s8[h];
  }
  __syncthreads();
  float macc = 0.f;
#pragma unroll
  for (int h = 0; h < 8; ++h) macc += ex[h] / (sred[0][h] + sred[1][h]);
  amean[(size_t)bi * 128 + j] = macc * 0.125f * ldf(adj, (size_t)bi * 128 + j, f);
}

// fused aggregate + Wo + LayerNorm. 4 rows/block (128 blocks), shfl LN.
__global__ __launch_bounds__(256) void node_fused(const float* amean, const float* msg,
                                                  const void* Wo, const void* Wob,
                                                  const void* node, const void* lng,
                                                  const void* lnb, const int* flag, void* dout) {
  const int f = *flag;
  const int r0 = blockIdx.x * 4;
  const int b = r0 >> 7;
  const int t = threadIdx.x;
  const int lane = t & 63, wave = t >> 6;
  __shared__ float am[512];
  __shared__ float sAgg[4][512];
  __shared__ float sw[4][4];
  __shared__ float sw2[4][4];
  am[t] = amean[(size_t)r0 * 128 + t];
  am[t + 256] = amean[(size_t)r0 * 128 + t + 256];
  __syncthreads();
  float a0[4] = {0.f, 0.f, 0.f, 0.f}, a1[4] = {0.f, 0.f, 0.f, 0.f};
#pragma unroll 2
  for (int jj = 0; jj < 128; ++jj) {
    const float* mr = msg + ((size_t)b * 128 + jj) * 512;
    float m0 = mr[t], m1 = mr[t + 256];
#pragma unroll
    for (int r = 0; r < 4; ++r) {
      a0[r] += am[r * 128 + jj] * m0;
      a1[r] += am[r * 128 + jj] * m1;
    }
  }
#pragma unroll
  for (int r = 0; r < 4; ++r) { sAgg[r][t] = a0[r]; sAgg[r][t + 256] = a1[r]; }
  __syncthreads();
  float v0[4] = {0.f, 0.f, 0.f, 0.f}, v1[4] = {0.f, 0.f, 0.f, 0.f};
  if (f) {
    const float* W = (const float*)Wo;
#pragma unroll 2
    for (int k = 0; k < 512; ++k) {
      float w0 = W[(size_t)k * 512 + t], w1 = W[(size_t)k * 512 + t + 256];
#pragma unroll
      for (int r = 0; r < 4; ++r) { v0[r] += sAgg[r][k] * w0; v1[r] += sAgg[r][k] * w1; }
    }
  } else {
    const bfloat* W = (const bfloat*)Wo;
#pragma unroll 2
    for (int k = 0; k < 512; ++k) {
      float w0 = __bfloat162float(W[(size_t)k * 512 + t]);
      float w1 = __bfloat162float(W[(size_t)k * 512 + t + 256]);
#pragma unroll
      for (int r = 0; r < 4; ++r) { v0[r] += sAgg[r][k] * w0; v1[r] += sAgg[r][k] * w1; }
    }
  }
  float wob0 = ldf(Wob, t, f), wob1 = ldf(Wob, t + 256, f);
#pragma unroll
  for (int r = 0; r < 4; ++r) {
    v0[r] += wob0 + ldf(node, (size_t)(r0 + r) * 512 + t, f);
    v1[r] += wob1 + ldf(node, (size_t)(r0 + r) * 512 + t + 256, f);
  }
  float s[4];
#pragma unroll
  for (int r = 0; r < 4; ++r) s[r] = v0[r] + v1[r];
#pragma unroll
  for (int o = 1; o < 64; o <<= 1)
#pragma unroll
    for (int r = 0; r < 4; ++r) s[r] += __shfl_xor(s[r], o);
  if (lane == 0) {
#pragma unroll
    for (int r = 0; r < 4; ++r) sw[wave][r] = s[r];
  }
  __syncthreads();
  float mean[4];
#pragma unroll
  for (int r = 0; r < 4; ++r)
    mean[r] = (sw[0][r] + sw[1][r] + sw[2][r] + sw[3][r]) * (1.f / 512.f);
#pragma unroll
  for (int r = 0; r < 4; ++r) {
    float d0 = v0[r] - mean[r], d1 = v1[r] - mean[r];
    s[r] = d0 * d0 + d1 * d1;
  }
#pragma unroll
  for (int o = 1; o < 64; o <<= 1)
#pragma unroll
    for (int r = 0; r < 4; ++r) s[r] += __shfl_xor(s[r], o);
  if (lane == 0) {
#pragma unroll
    for (int r = 0; r < 4; ++r) sw2[wave][r] = s[r];
  }
  __syncthreads();
  float g0v = ldf(lng, t, f), g1v = ldf(lng, t + 256, f);
  float b0v = ldf(lnb, t, f), b1v = ldf(lnb, t + 256, f);
#pragma unroll
  for (int r = 0; r < 4; ++r) {
    float var = (sw2[0][r] + sw2[1][r] + sw2[2][r] + sw2[3][r]) * (1.f / 512.f);
    float inv = rsqrtf(var + 1e-5f);
    stf(dout, (size_t)(r0 + r) * 512 + t, (v0[r] - mean[r]) * inv * g0v + b0v, f);
    stf(dout, (size_t)(r0 + r) * 512 + t + 256, (v1[r] - mean[r]) * inv * g1v + b1v, f);
  }
}

extern "C" void kernel_launch(void* const* d_in, const int* in_sizes, int n_in, void* d_out,
                              int out_size, void* d_ws, size_t ws_size, hipStream_t stream) {
  (void)in_sizes; (void)n_in; (void)out_size;
  const void* node = d_in[0];
  const void* edge = d_in[1];
  const void* adj = d_in[2];
  const void* Wn_w = d_in[3];
  const void* Wn_b = d_in[4];
  const void* We1_w = d_in[5];
  const void* We1_b = d_in[6];
  const void* We2_w = d_in[7];
  // d_in[8] = We2_b: constant over j -> cancels in softmax, unused.
  const void* Wm_w = d_in[9];
  const void* Wm_b = d_in[10];
  const void* Wu1_w = d_in[11];
  const void* Wu1_b = d_in[12];
  const void* Wu2_w = d_in[13];
  const void* Wu2_b = d_in[14];
  const void* Wo_w = d_in[15];
  const void* Wo_b = d_in[16];
  const void* ln_g = d_in[17];
  const void* ln_b = d_in[18];

  char* w = (char*)d_ws;
  int* flag = (int*)w;        w += 256;
  float* h = (float*)w;       w += 262144 * 4;
  float* P1 = (float*)w;      w += 262144 * 4;
  float* Q1 = (float*)w;      w += 262144 * 4;
  float* P2 = (float*)w;      w += 262144 * 4;
  float* Q2 = (float*)w;      w += 262144 * 4;
  float* msg = (float*)w;     w += 262144 * 4;
  float* logits4 = (float*)w; w += (size_t)4 * 524288 * 4;  // [4][512][128][8] fp32 = 8MB
  float* amean = (float*)w;   w += 65536 * 4;
  bfloat* WtA = (bfloat*)w;   w += 262144 * 2;
  bfloat* WtB = (bfloat*)w;   w += 262144 * 2;
  bfloat* WtC = (bfloat*)w;   w += 262144 * 2;
  bfloat* WtD = (bfloat*)w;   w += 262144 * 2;
  bfloat* WtE = (bfloat*)w;   w += 262144 * 2;
  bfloat* WtF = (bfloat*)w;   w += 262144 * 2;
  bfloat* WtG = (bfloat*)w;   w += 262144 * 2;
  bfloat* WtH = (bfloat*)w;   w += 262144 * 2;
  bfloat* hb = (bfloat*)w;    w += 262144 * 2;
  bfloat* u_ws = (bfloat*)w;  w += (size_t)65536 * 1024;  // 64MB: u linear, 1024B rows
  const int uws_ok = (ws_size >= (size_t)(w - (char*)d_ws)) ? 1 : 0;
  if (!uws_ok) u_ws = nullptr;

  detect_dtype<<<1, 256, 0, stream>>>((const unsigned short*)node, flag);
  prep<<<17024, 256, 0, stream>>>((const float*)edge, We1_w, Wu1_w, Wu2_w, Wm_w, node,
                                  Wn_w, Wn_b, flag, d_out, WtA, WtB, WtC, WtD, WtE, WtF,
                                  WtG, WtH, h, hb);
  fused5_mfma<<<80, 256, 0, stream>>>(hb, WtD, WtE, WtF, WtG, WtH, We1_b, Wu1_b, Wm_b, flag,
                                      P1, Q1, P2, Q2, msg);
  k3_edge_mlp<<<4096, 256, 0, stream>>>(edge, WtA, WtB, P1, Q1, P2, Q2, We2_w, flag,
                                        logits4, u_ws, d_out);
  softmax_mean<<<512, 128, 0, stream>>>(logits4, adj, flag, amean);
  node_fused<<<128, 256, 0, stream>>>(amean, msg, Wo_w, Wo_b, node, ln_g, ln_b, flag, d_out);
  if (uws_ok)
    k6_ws<<<2048, 256, 0, stream>>>(u_ws, WtC, Wu2_b, edge, flag, d_out);
  else
    k6_chunk<<<1024, 512, 0, stream>>>(WtC, Wu2_b, edge, flag, d_out);
}